// Round 8
// baseline (1156.081 us; speedup 1.0000x reference)
//
#include <hip/hip_runtime.h>
#include <hip/hip_fp16.h>

#define N_NODES 100000
#define E_EDGES 3200000
#define F_IN 11
#define F_H 64
#define F_E 32

#define BUCKETS ((N_NODES + 255) >> 8)   // 391 coarse buckets (dst>>8)
#define CAP 9216                         // slack bucket capacity (mean 8192, +11 sigma)
#define CHUNK_A 8192
#define NWG_A ((E_EDGES + CHUNK_A - 1) / CHUNK_A)  // 391

// ---------------- binning: pairs = (src | local_dst<<17), slack buckets ----------------

__global__ void binA_kernel(const int* __restrict__ src,
                            const int* __restrict__ dst,
                            int* __restrict__ cursor,
                            unsigned int* __restrict__ pairs) {
    __shared__ int lh[BUCKETS];
    int t = threadIdx.x;
    for (int i = t; i < BUCKETS; i += 512) lh[i] = 0;
    __syncthreads();
    int e0 = blockIdx.x * CHUNK_A;
    int e1 = min(e0 + CHUNK_A, E_EDGES);
    for (int i = e0 + t; i < e1; i += 512)
        atomicAdd(&lh[dst[i] >> 8], 1);
    __syncthreads();
    for (int i = t; i < BUCKETS; i += 512) {
        int c = lh[i];
        lh[i] = (c > 0) ? (i * CAP + atomicAdd(&cursor[i], c)) : 0;
    }
    __syncthreads();
    for (int i = e0 + t; i < e1; i += 512) {
        int d = dst[i];
        int b = d >> 8;
        int pos = atomicAdd(&lh[b], 1);
        pairs[pos] = (unsigned int)src[i] | (((unsigned int)(d & 255)) << 17);
    }
}

// ---------------- fp16 conversion of x ----------------
__global__ void convert_x_kernel(const float* __restrict__ x, __half* __restrict__ xh) {
    int tid = blockIdx.x * blockDim.x + threadIdx.x;
    if (tid >= N_NODES * 12) return;
    int n = tid / 12;
    int f = tid - n * 12;
    xh[tid] = __float2half((f < F_IN) ? x[n * F_IN + f] : 0.0f);
}

// ---------------- layer-1 aggregation directly from pairs ----------------
// WG = (bucket, node-half). Scans bucket's pairs; accumulates its 128 nodes
// into LDS agg[128][13] (pad 13 spreads banks) + degree hist; coalesced flush.
__global__ void binAgg1_kernel(const unsigned int* __restrict__ pairs,
                               const int* __restrict__ cursor,
                               const __half2* __restrict__ xh2,
                               int* __restrict__ deg_i,
                               float* __restrict__ agg1) {
    __shared__ float lagg[128 * 13];
    __shared__ int lhist[128];
    int b = blockIdx.x >> 1;
    int hhalf = blockIdx.x & 1;
    int t = threadIdx.x;
    for (int i = t; i < 128 * 13; i += 256) lagg[i] = 0.0f;
    if (t < 128) lhist[t] = 0;
    __syncthreads();
    int start = b * CAP;
    int end = start + cursor[b];
    for (int i = start + t; i < end; i += 256) {
        unsigned int p = pairs[i];
        int ld = (int)(p >> 17);
        if ((ld >> 7) == hhalf) {
            int s = (int)(p & 0x1FFFFu);
            int r = ld & 127;
            atomicAdd(&lhist[r], 1);
            const __half2* xr = xh2 + s * 6;
            #pragma unroll
            for (int k = 0; k < 6; ++k) {
                float2 v = __half22float2(xr[k]);
                atomicAdd(&lagg[r * 13 + 2 * k], v.x);
                atomicAdd(&lagg[r * 13 + 2 * k + 1], v.y);
            }
        }
    }
    __syncthreads();
    int node0 = (b << 8) + (hhalf << 7);
    for (int i = t; i < 128 * 12; i += 256) {
        int r = i / 12;
        int f = i - 12 * r;
        int node = node0 + r;
        if (node < N_NODES) agg1[node * 12 + f] = lagg[r * 13 + f];
    }
    if (t < 128 && node0 + t < N_NODES) deg_i[node0 + t] = lhist[t];
}

// ---------------- layer 1 node: h = relu(agg1/deg*W1l + x*W1r + b1) -> fp16 ----------
__global__ void layer1_node_kernel(const float* __restrict__ x,
                                   const float* __restrict__ agg1,
                                   const int* __restrict__ deg_i,
                                   const float* __restrict__ W1l,
                                   const float* __restrict__ W1r,
                                   const float* __restrict__ b1,
                                   __half* __restrict__ hh) {
    int tid = blockIdx.x * blockDim.x + threadIdx.x;
    int n = tid >> 6;
    int j = tid & 63;
    if (n >= N_NODES) return;
    float invd = 1.0f / fmaxf((float)deg_i[n], 1.0f);
    float acc = b1[j];
    #pragma unroll
    for (int f = 0; f < F_IN; ++f) {
        float a = agg1[n * 12 + f] * invd;
        float xv = x[n * F_IN + f];
        acc += a * W1l[f * F_H + j] + xv * W1r[f * F_H + j];
    }
    hh[n * F_H + j] = __float2half(fmaxf(acc, 0.0f));
}

// ---------------- dual projection: p2 slices fp16, r2 = h@W2r + b2 fp32 ----------
__global__ void proj2_dual_kernel(const __half2* __restrict__ hh2,
                                  const float* __restrict__ W2l,
                                  const float* __restrict__ W2r,
                                  const float* __restrict__ b2,
                                  __half* __restrict__ p2a, __half* __restrict__ p2b,
                                  float* __restrict__ r2) {
    int tid = blockIdx.x * blockDim.x + threadIdx.x;
    int n = tid >> 5;
    int j = tid & 31;
    if (n >= N_NODES) return;
    const __half2* hrow = hh2 + n * 32;
    float accL = 0.0f, accR = 0.0f;
    #pragma unroll
    for (int k2 = 0; k2 < 32; ++k2) {
        float2 hv = __half22float2(hrow[k2]);
        accL += hv.x * W2l[(2 * k2) * F_E + j] + hv.y * W2l[(2 * k2 + 1) * F_E + j];
        accR += hv.x * W2r[(2 * k2) * F_E + j] + hv.y * W2r[(2 * k2 + 1) * F_E + j];
    }
    r2[n * F_E + j] = accR + b2[j];
    int jj = j & 15;
    __half* pd = (j < 16) ? p2a : p2b;
    pd[n * 16 + jj] = __float2half(accL);
}

// ---------------- layer-2 slice aggregation directly from pairs ----------------
// WG = (bucket, node-half). LDS agg[128][17] += p2s[src] (3.2MB L2-resident slice).
__global__ void binAgg2_kernel(const unsigned int* __restrict__ pairs,
                               const int* __restrict__ cursor,
                               const __half2* __restrict__ p2s,   // [N][8] half2
                               float* __restrict__ agg2s) {       // [N][16] fp32
    __shared__ float lagg[128 * 17];
    int b = blockIdx.x >> 1;
    int hhalf = blockIdx.x & 1;
    int t = threadIdx.x;
    for (int i = t; i < 128 * 17; i += 256) lagg[i] = 0.0f;
    __syncthreads();
    int start = b * CAP;
    int end = start + cursor[b];
    for (int i = start + t; i < end; i += 256) {
        unsigned int p = pairs[i];
        int ld = (int)(p >> 17);
        if ((ld >> 7) == hhalf) {
            int s = (int)(p & 0x1FFFFu);
            int r = ld & 127;
            const __half2* pr = p2s + s * 8;
            #pragma unroll
            for (int k = 0; k < 8; ++k) {
                float2 v = __half22float2(pr[k]);
                atomicAdd(&lagg[r * 17 + 2 * k], v.x);
                atomicAdd(&lagg[r * 17 + 2 * k + 1], v.y);
            }
        }
    }
    __syncthreads();
    int node0 = (b << 8) + (hhalf << 7);
    for (int i = t; i < 128 * 16; i += 256) {
        int r = i >> 4;
        int f = i & 15;
        int node = node0 + r;
        if (node < N_NODES) agg2s[node * 16 + f] = lagg[r * 17 + f];
    }
}

// ---------------- final: emb = relu(agg2/deg + r2), logits ----------------
__global__ void final_kernel(const float* __restrict__ agg2a,
                             const float* __restrict__ agg2b,
                             const float* __restrict__ r2,
                             const int* __restrict__ deg_i,
                             const float* __restrict__ Wc,
                             const float* __restrict__ bc,
                             float* __restrict__ emb,
                             float* __restrict__ logits) {
    int tid = blockIdx.x * blockDim.x + threadIdx.x;
    int n = tid >> 5;
    int j = tid & 31;
    if (n >= N_NODES) return;
    float invd = 1.0f / fmaxf((float)deg_i[n], 1.0f);
    float sum = (j < 16) ? agg2a[n * 16 + j] : agg2b[n * 16 + (j - 16)];
    float e = fmaxf(sum * invd + r2[n * F_E + j], 0.0f);
    emb[n * F_E + j] = e;
    float c0 = e * Wc[j * 3 + 0];
    float c1 = e * Wc[j * 3 + 1];
    float c2 = e * Wc[j * 3 + 2];
    #pragma unroll
    for (int m = 1; m < 32; m <<= 1) {
        c0 += __shfl_xor(c0, m);
        c1 += __shfl_xor(c1, m);
        c2 += __shfl_xor(c2, m);
    }
    if (j == 0) {
        logits[n * 3 + 0] = c0 + bc[0];
        logits[n * 3 + 1] = c1 + bc[1];
        logits[n * 3 + 2] = c2 + bc[2];
    }
}

extern "C" void kernel_launch(void* const* d_in, const int* in_sizes, int n_in,
                              void* d_out, int out_size, void* d_ws, size_t ws_size,
                              hipStream_t stream) {
    const float* x   = (const float*)d_in[0];
    const int*   ei  = (const int*)d_in[1];
    const float* W1l = (const float*)d_in[2];
    const float* W1r = (const float*)d_in[3];
    const float* b1  = (const float*)d_in[4];
    const float* W2l = (const float*)d_in[5];
    const float* W2r = (const float*)d_in[6];
    const float* b2  = (const float*)d_in[7];
    const float* Wc  = (const float*)d_in[8];
    const float* bc  = (const float*)d_in[9];

    const int* src = ei;
    const int* dst = ei + E_EDGES;

    float* out    = (float*)d_out;
    float* logits = out;
    float* emb    = out + (size_t)N_NODES * 3;

    // ws layout (4B units), total ~54 MB:
    //   deg_i   : N
    //   cursor  : 512
    //   pairs   : BUCKETS*CAP (3.60M)
    //   agg1    : 12N fp32
    //   hh      : 32N units (64N halves)  -- aliased by agg2a(16N)+agg2b(16N) after proj2
    //   p2a     : 8N units ([N,16] fp16)
    //   p2b     : 8N units
    //   r2      : 32N fp32
    //   xh      : 6N units (12N halves)
    int* ws_i   = (int*)d_ws;
    int* deg_i  = ws_i;
    int* cursor = ws_i + N_NODES;
    unsigned int* pairs = (unsigned int*)(ws_i + N_NODES + 512);
    int* base2  = ws_i + N_NODES + 512 + (size_t)BUCKETS * CAP;
    float* agg1 = (float*)base2;                               // 12N
    float* hreg = (float*)(base2 + (size_t)12 * N_NODES);      // 32N
    __half* hh  = (__half*)hreg;
    float* agg2a = hreg;                                       // alias (hh dead after proj2)
    float* agg2b = hreg + (size_t)16 * N_NODES;
    __half* p2a = (__half*)(base2 + (size_t)44 * N_NODES);     // 8N units
    __half* p2b = (__half*)(base2 + (size_t)52 * N_NODES);     // 8N units
    float* r2   = (float*)(base2 + (size_t)60 * N_NODES);      // 32N
    __half* xh  = (__half*)(base2 + (size_t)92 * N_NODES);     // 6N units

    hipMemsetAsync(cursor, 0, 512 * sizeof(int), stream);

    const int BS = 256;

    convert_x_kernel<<<(N_NODES * 12 + BS - 1) / BS, BS, 0, stream>>>(x, xh);
    binA_kernel<<<NWG_A, 512, 0, stream>>>(src, dst, cursor, pairs);
    binAgg1_kernel<<<BUCKETS * 2, BS, 0, stream>>>(
        pairs, cursor, (const __half2*)xh, deg_i, agg1);
    layer1_node_kernel<<<(N_NODES * 64 + BS - 1) / BS, BS, 0, stream>>>(
        x, agg1, deg_i, W1l, W1r, b1, hh);
    proj2_dual_kernel<<<(N_NODES * 32 + BS - 1) / BS, BS, 0, stream>>>(
        (const __half2*)hh, W2l, W2r, b2, p2a, p2b, r2);
    binAgg2_kernel<<<BUCKETS * 2, BS, 0, stream>>>(
        pairs, cursor, (const __half2*)p2a, agg2a);
    binAgg2_kernel<<<BUCKETS * 2, BS, 0, stream>>>(
        pairs, cursor, (const __half2*)p2b, agg2b);
    final_kernel<<<(N_NODES * 32 + BS - 1) / BS, BS, 0, stream>>>(
        agg2a, agg2b, r2, deg_i, Wc, bc, emb, logits);
}

// Round 9
// 325.272 us; speedup vs baseline: 3.5542x; 3.5542x over previous
//
#include <hip/hip_runtime.h>
#include <hip/hip_fp16.h>
#include <hip/hip_fp8.h>

#define N_NODES 100000
#define E_EDGES 3200000
#define F_IN 11
#define F_H 64
#define F_E 32

#define BUCKETS ((N_NODES + 255) >> 8)   // 391 coarse buckets (dst>>8)
#define CAP 9216                         // slack bucket capacity (mean ~8184, +11 sigma)
#define CHUNK_A 12288
#define NWG_A ((E_EDGES + CHUNK_A - 1) / CHUNK_A)  // 261

// ---------------- CSR construction (slack buckets, no counting pass) ----------------

__global__ void binA_kernel(const int* __restrict__ src,
                            const int* __restrict__ dst,
                            int* __restrict__ cursor,
                            unsigned int* __restrict__ pairs) {
    __shared__ int lh[BUCKETS];
    int t = threadIdx.x;
    for (int i = t; i < BUCKETS; i += 256) lh[i] = 0;
    __syncthreads();
    int e0 = blockIdx.x * CHUNK_A;
    int e1 = min(e0 + CHUNK_A, E_EDGES);
    for (int i = e0 + t; i < e1; i += 256)
        atomicAdd(&lh[dst[i] >> 8], 1);
    __syncthreads();
    for (int i = t; i < BUCKETS; i += 256) {
        int c = lh[i];
        lh[i] = (c > 0) ? (i * CAP + atomicAdd(&cursor[i], c)) : 0;
    }
    __syncthreads();
    for (int i = e0 + t; i < e1; i += 256) {
        int d = dst[i];
        int b = d >> 8;
        int pos = atomicAdd(&lh[b], 1);
        pairs[pos] = (unsigned int)src[i] | (((unsigned int)(d & 255)) << 17);
    }
}

__global__ void binB_kernel(const unsigned int* __restrict__ pairs,
                            const int* __restrict__ cursor,
                            int* __restrict__ deg_i,
                            int* __restrict__ offsets,
                            int* __restrict__ csr_src) {
    __shared__ int lhist[256];
    __shared__ int lscan[256];
    __shared__ int lcur[256];
    int b = blockIdx.x;
    int t = threadIdx.x;
    lhist[t] = 0;
    __syncthreads();
    int start = b * CAP;
    int end = start + cursor[b];
    for (int i = start + t; i < end; i += 256)
        atomicAdd(&lhist[pairs[i] >> 17], 1);
    __syncthreads();
    int cnt = lhist[t];
    lscan[t] = cnt;
    __syncthreads();
    int incl = cnt;
    for (int off = 1; off < 256; off <<= 1) {
        int tmp = (t >= off) ? lscan[t - off] : 0;
        __syncthreads();
        incl += tmp;
        lscan[t] = incl;
        __syncthreads();
    }
    int ex = start + incl - cnt;  // offset within slack csr layout
    int node = (b << 8) + t;
    if (node < N_NODES) {
        deg_i[node] = cnt;
        offsets[node] = ex;
    }
    lcur[t] = ex;
    __syncthreads();
    for (int i = start + t; i < end; i += 256) {
        unsigned int p = pairs[i];
        int pos = atomicAdd(&lcur[p >> 17], 1);
        csr_src[pos] = (int)(p & 0x1FFFFu);
    }
}

// ---------------- fp16 conversion of x ----------------
__global__ void convert_x_kernel(const float* __restrict__ x, __half* __restrict__ xh) {
    int tid = blockIdx.x * blockDim.x + threadIdx.x;
    if (tid >= N_NODES * 12) return;
    int n = tid / 12;
    int f = tid - n * 12;
    xh[tid] = __float2half((f < F_IN) ? x[n * F_IN + f] : 0.0f);
}

// ---------------- layer 1 ----------------

// gather via half2: 8 lanes/node, lanes 0..5 active (6 half2 = 12 halves/row)
__global__ void gather1_kernel(const int* __restrict__ csr_src,
                               const int* __restrict__ offsets,
                               const int* __restrict__ deg_i,
                               const __half2* __restrict__ xh2,
                               float* __restrict__ agg1) {
    int tid = blockIdx.x * blockDim.x + threadIdx.x;
    int n = tid >> 3;
    int f2 = tid & 7;
    if (n >= N_NODES || f2 >= 6) return;
    int start = offsets[n];
    int end = start + deg_i[n];
    float2 a0 = {0.f, 0.f}, a1 = {0.f, 0.f}, a2 = {0.f, 0.f}, a3 = {0.f, 0.f};
    int i = start;
    for (; i + 4 <= end; i += 4) {
        int s0 = csr_src[i], s1 = csr_src[i + 1], s2 = csr_src[i + 2], s3 = csr_src[i + 3];
        float2 v0 = __half22float2(xh2[s0 * 6 + f2]);
        float2 v1 = __half22float2(xh2[s1 * 6 + f2]);
        float2 v2 = __half22float2(xh2[s2 * 6 + f2]);
        float2 v3 = __half22float2(xh2[s3 * 6 + f2]);
        a0.x += v0.x; a0.y += v0.y;
        a1.x += v1.x; a1.y += v1.y;
        a2.x += v2.x; a2.y += v2.y;
        a3.x += v3.x; a3.y += v3.y;
    }
    for (; i < end; ++i) {
        float2 v = __half22float2(xh2[csr_src[i] * 6 + f2]);
        a0.x += v.x; a0.y += v.y;
    }
    float2 r;
    r.x = a0.x + a1.x + a2.x + a3.x;
    r.y = a0.y + a1.y + a2.y + a3.y;
    ((float2*)agg1)[n * 6 + f2] = r;   // agg1 padded to 12 floats/node
}

// h = relu(agg1/deg * W1l + x * W1r + b1) stored fp16; thread = (n, j<64)
__global__ void layer1_node_kernel(const float* __restrict__ x,
                                   const float* __restrict__ agg1,
                                   const int* __restrict__ deg_i,
                                   const float* __restrict__ W1l,
                                   const float* __restrict__ W1r,
                                   const float* __restrict__ b1,
                                   __half* __restrict__ hh) {
    int tid = blockIdx.x * blockDim.x + threadIdx.x;
    int n = tid >> 6;
    int j = tid & 63;
    if (n >= N_NODES) return;
    float invd = 1.0f / fmaxf((float)deg_i[n], 1.0f);
    float acc = b1[j];
    #pragma unroll
    for (int f = 0; f < F_IN; ++f) {
        float a = agg1[n * 12 + f] * invd;
        float xv = x[n * F_IN + f];
        acc += a * W1l[f * F_H + j] + xv * W1r[f * F_H + j];
    }
    hh[n * F_H + j] = __float2half(fmaxf(acc, 0.0f));
}

// ---------------- dual projection: p8 = fp8(h@W2l) [N,32]=3.2MB, r2 = h@W2r+b2 fp32 --
__global__ void proj2_dual_kernel(const __half2* __restrict__ hh2,
                                  const float* __restrict__ W2l,
                                  const float* __restrict__ W2r,
                                  const float* __restrict__ b2,
                                  unsigned char* __restrict__ p8,
                                  float* __restrict__ r2) {
    int tid = blockIdx.x * blockDim.x + threadIdx.x;
    int n = tid >> 5;
    int j = tid & 31;
    if (n >= N_NODES) return;
    const __half2* hrow = hh2 + n * 32;
    float accL = 0.0f, accR = 0.0f;
    #pragma unroll
    for (int k2 = 0; k2 < 32; ++k2) {
        float2 hv = __half22float2(hrow[k2]);
        accL += hv.x * W2l[(2 * k2) * F_E + j] + hv.y * W2l[(2 * k2 + 1) * F_E + j];
        accR += hv.x * W2r[(2 * k2) * F_E + j] + hv.y * W2r[(2 * k2 + 1) * F_E + j];
    }
    r2[n * F_E + j] = accR + b2[j];
    __hip_fp8_e4m3 q(accL);
    p8[n * F_E + j] = (unsigned char)q.__x;
}

// decode 4 packed fp8 e4m3 -> 4 floats
__device__ inline float4 fp8x4_to_f32(unsigned int w) {
    __hip_fp8_e4m3 a, b, c, d;
    a.__x = (__hip_fp8_storage_t)(w & 0xFF);
    b.__x = (__hip_fp8_storage_t)((w >> 8) & 0xFF);
    c.__x = (__hip_fp8_storage_t)((w >> 16) & 0xFF);
    d.__x = (__hip_fp8_storage_t)((w >> 24) & 0xFF);
    return make_float4((float)a, (float)b, (float)c, (float)d);
}

// ---------------- layer 2 fused: fp8 gather (L2-resident 3.2MB) + relu + logits ------
// 8 lanes/node; lane l owns features 4l..4l+3 (one uint = 4 fp8 per neighbor).
__global__ void layer2_fused_kernel(const int* __restrict__ csr_src,
                                    const int* __restrict__ offsets,
                                    const int* __restrict__ deg_i,
                                    const unsigned int* __restrict__ p8u,  // [N][8] uint
                                    const float* __restrict__ r2,
                                    const float* __restrict__ Wc,
                                    const float* __restrict__ bc,
                                    float* __restrict__ emb,
                                    float* __restrict__ logits) {
    int tid = blockIdx.x * blockDim.x + threadIdx.x;
    int n = tid >> 3;
    int l = tid & 7;
    if (n >= N_NODES) return;
    int start = offsets[n];
    int cnt = deg_i[n];
    int end = start + cnt;
    float ax = 0.f, ay = 0.f, az = 0.f, aw = 0.f;
    float bx = 0.f, by = 0.f, bz = 0.f, bw = 0.f;
    int i = start;
    for (; i + 4 <= end; i += 4) {
        int s0 = csr_src[i], s1 = csr_src[i + 1], s2 = csr_src[i + 2], s3 = csr_src[i + 3];
        unsigned int w0 = p8u[s0 * 8 + l];
        unsigned int w1 = p8u[s1 * 8 + l];
        unsigned int w2 = p8u[s2 * 8 + l];
        unsigned int w3 = p8u[s3 * 8 + l];
        float4 v0 = fp8x4_to_f32(w0);
        float4 v1 = fp8x4_to_f32(w1);
        float4 v2 = fp8x4_to_f32(w2);
        float4 v3 = fp8x4_to_f32(w3);
        ax += v0.x + v2.x; ay += v0.y + v2.y; az += v0.z + v2.z; aw += v0.w + v2.w;
        bx += v1.x + v3.x; by += v1.y + v3.y; bz += v1.z + v3.z; bw += v1.w + v3.w;
    }
    for (; i < end; ++i) {
        float4 v = fp8x4_to_f32(p8u[csr_src[i] * 8 + l]);
        ax += v.x; ay += v.y; az += v.z; aw += v.w;
    }
    float invd = 1.0f / fmaxf((float)cnt, 1.0f);
    const float* rrow = r2 + n * F_E + 4 * l;
    float4 e;
    e.x = fmaxf((ax + bx) * invd + rrow[0], 0.0f);
    e.y = fmaxf((ay + by) * invd + rrow[1], 0.0f);
    e.z = fmaxf((az + bz) * invd + rrow[2], 0.0f);
    e.w = fmaxf((aw + bw) * invd + rrow[3], 0.0f);
    ((float4*)emb)[n * 8 + l] = e;
    const float* wc = Wc + (4 * l) * 3;
    float c0 = e.x * wc[0] + e.y * wc[3] + e.z * wc[6] + e.w * wc[9];
    float c1 = e.x * wc[1] + e.y * wc[4] + e.z * wc[7] + e.w * wc[10];
    float c2 = e.x * wc[2] + e.y * wc[5] + e.z * wc[8] + e.w * wc[11];
    #pragma unroll
    for (int m = 1; m < 8; m <<= 1) {
        c0 += __shfl_xor(c0, m);
        c1 += __shfl_xor(c1, m);
        c2 += __shfl_xor(c2, m);
    }
    if (l == 0) {
        logits[n * 3 + 0] = c0 + bc[0];
        logits[n * 3 + 1] = c1 + bc[1];
        logits[n * 3 + 2] = c2 + bc[2];
    }
}

extern "C" void kernel_launch(void* const* d_in, const int* in_sizes, int n_in,
                              void* d_out, int out_size, void* d_ws, size_t ws_size,
                              hipStream_t stream) {
    const float* x   = (const float*)d_in[0];
    const int*   ei  = (const int*)d_in[1];
    const float* W1l = (const float*)d_in[2];
    const float* W1r = (const float*)d_in[3];
    const float* b1  = (const float*)d_in[4];
    const float* W2l = (const float*)d_in[5];
    const float* W2r = (const float*)d_in[6];
    const float* b2  = (const float*)d_in[7];
    const float* Wc  = (const float*)d_in[8];
    const float* bc  = (const float*)d_in[9];

    const int* src = ei;
    const int* dst = ei + E_EDGES;

    float* out    = (float*)d_out;
    float* logits = out;
    float* emb    = out + (size_t)N_NODES * 3;

    // ws layout (4B units), total ~53 MB:
    //   deg_i   : N
    //   offsets : N
    //   cursor  : 512
    //   csr_src : BUCKETS*CAP (3.60M)
    //   region1 : BUCKETS*CAP: pairs (binA..binB) -> hh 32N (layer1..proj2)
    //   r2      : 32N fp32
    //   p8      : 8N units ([N,32] fp8)
    //   xh      : 6N units (12N halves)
    //   agg1    : 12N floats
    int* ws_i     = (int*)d_ws;
    int* deg_i    = ws_i;
    int* offsets  = ws_i + N_NODES;
    int* cursor   = ws_i + 2 * N_NODES;
    int* csr_src  = cursor + 512;
    int* region1  = csr_src + (size_t)BUCKETS * CAP;
    unsigned int* pairs = (unsigned int*)region1;
    __half* hh    = (__half*)region1;                         // 64N halves (alias of pairs)
    int* base2    = region1 + (size_t)BUCKETS * CAP;
    float* r2     = (float*)base2;                            // 32N
    unsigned char* p8 = (unsigned char*)(base2 + (size_t)32 * N_NODES);  // 8N units
    __half* xh    = (__half*)(base2 + (size_t)40 * N_NODES);  // 6N units
    float* agg1   = (float*)(base2 + (size_t)46 * N_NODES);   // 12N

    hipMemsetAsync(cursor, 0, 512 * sizeof(int), stream);

    const int BS = 256;

    convert_x_kernel<<<(N_NODES * 12 + BS - 1) / BS, BS, 0, stream>>>(x, xh);
    binA_kernel<<<NWG_A, BS, 0, stream>>>(src, dst, cursor, pairs);
    binB_kernel<<<BUCKETS, BS, 0, stream>>>(pairs, cursor, deg_i, offsets, csr_src);

    gather1_kernel<<<(N_NODES * 8 + BS - 1) / BS, BS, 0, stream>>>(
        csr_src, offsets, deg_i, (const __half2*)xh, agg1);
    layer1_node_kernel<<<(N_NODES * 64 + BS - 1) / BS, BS, 0, stream>>>(
        x, agg1, deg_i, W1l, W1r, b1, hh);
    proj2_dual_kernel<<<(N_NODES * 32 + BS - 1) / BS, BS, 0, stream>>>(
        (const __half2*)hh, W2l, W2r, b2, p8, r2);
    layer2_fused_kernel<<<(N_NODES * 8 + BS - 1) / BS, BS, 0, stream>>>(
        csr_src, offsets, deg_i, (const unsigned int*)p8, r2, Wc, bc, emb, logits);
}

// Round 10
// 310.419 us; speedup vs baseline: 3.7243x; 1.0478x over previous
//
#include <hip/hip_runtime.h>
#include <hip/hip_fp16.h>
#include <hip/hip_fp8.h>

#define N_NODES 100000
#define E_EDGES 3200000
#define F_IN 11
#define F_H 64
#define F_E 32

#define BUCKETS ((N_NODES + 255) >> 8)   // 391 coarse buckets (dst>>8)
#define CAP 9216                         // slack bucket capacity (mean ~8184, +11 sigma)
#define CHUNK_A 12288
#define NWG_A ((E_EDGES + CHUNK_A - 1) / CHUNK_A)  // 261

// ---------------- CSR construction (slack buckets, no counting pass) ----------------
// 1024-thread blocks: same chunk/run-length (write-amp stays ~2x) but 16 waves/CU.
__global__ void binA_kernel(const int* __restrict__ src,
                            const int* __restrict__ dst,
                            int* __restrict__ cursor,
                            unsigned int* __restrict__ pairs) {
    __shared__ int lh[BUCKETS];
    int t = threadIdx.x;
    for (int i = t; i < BUCKETS; i += 1024) lh[i] = 0;
    __syncthreads();
    int e0 = blockIdx.x * CHUNK_A;
    int e1 = min(e0 + CHUNK_A, E_EDGES);
    for (int i = e0 + t; i < e1; i += 1024)
        atomicAdd(&lh[dst[i] >> 8], 1);
    __syncthreads();
    for (int i = t; i < BUCKETS; i += 1024) {
        int c = lh[i];
        lh[i] = (c > 0) ? (i * CAP + atomicAdd(&cursor[i], c)) : 0;
    }
    __syncthreads();
    for (int i = e0 + t; i < e1; i += 1024) {
        int d = dst[i];
        int b = d >> 8;
        int pos = atomicAdd(&lh[b], 1);
        pairs[pos] = (unsigned int)src[i] | (((unsigned int)(d & 255)) << 17);
    }
}

// 512-thread blocks (scan portion uses first 256 threads; barriers are uniform).
__global__ void binB_kernel(const unsigned int* __restrict__ pairs,
                            const int* __restrict__ cursor,
                            int* __restrict__ deg_i,
                            int* __restrict__ offsets,
                            int* __restrict__ csr_src) {
    __shared__ int lhist[256];
    __shared__ int lscan[256];
    __shared__ int lcur[256];
    int b = blockIdx.x;
    int t = threadIdx.x;
    if (t < 256) lhist[t] = 0;
    __syncthreads();
    int start = b * CAP;
    int end = start + cursor[b];
    for (int i = start + t; i < end; i += 512)
        atomicAdd(&lhist[pairs[i] >> 17], 1);
    __syncthreads();
    int cnt = (t < 256) ? lhist[t] : 0;
    if (t < 256) lscan[t] = cnt;
    __syncthreads();
    int incl = cnt;
    for (int off = 1; off < 256; off <<= 1) {
        int tmp = (t < 256 && t >= off) ? lscan[t - off] : 0;
        __syncthreads();
        if (t < 256) {
            incl += tmp;
            lscan[t] = incl;
        }
        __syncthreads();
    }
    if (t < 256) {
        int ex = start + incl - cnt;  // offset within slack csr layout
        int node = (b << 8) + t;
        if (node < N_NODES) {
            deg_i[node] = cnt;
            offsets[node] = ex;
        }
        lcur[t] = ex;
    }
    __syncthreads();
    for (int i = start + t; i < end; i += 512) {
        unsigned int p = pairs[i];
        int pos = atomicAdd(&lcur[p >> 17], 1);
        csr_src[pos] = (int)(p & 0x1FFFFu);
    }
}

// ---------------- fp16 conversion of x ----------------
__global__ void convert_x_kernel(const float* __restrict__ x, __half* __restrict__ xh) {
    int tid = blockIdx.x * blockDim.x + threadIdx.x;
    if (tid >= N_NODES * 12) return;
    int n = tid / 12;
    int f = tid - n * 12;
    xh[tid] = __float2half((f < F_IN) ? x[n * F_IN + f] : 0.0f);
}

// ---------------- layer 1 ----------------

// gather via half2: 8 lanes/node, lanes 0..5 active (6 half2 = 12 halves/row)
__global__ void gather1_kernel(const int* __restrict__ csr_src,
                               const int* __restrict__ offsets,
                               const int* __restrict__ deg_i,
                               const __half2* __restrict__ xh2,
                               float* __restrict__ agg1) {
    int tid = blockIdx.x * blockDim.x + threadIdx.x;
    int n = tid >> 3;
    int f2 = tid & 7;
    if (n >= N_NODES || f2 >= 6) return;
    int start = offsets[n];
    int end = start + deg_i[n];
    float2 a0 = {0.f, 0.f}, a1 = {0.f, 0.f}, a2 = {0.f, 0.f}, a3 = {0.f, 0.f};
    int i = start;
    for (; i + 4 <= end; i += 4) {
        int s0 = csr_src[i], s1 = csr_src[i + 1], s2 = csr_src[i + 2], s3 = csr_src[i + 3];
        float2 v0 = __half22float2(xh2[s0 * 6 + f2]);
        float2 v1 = __half22float2(xh2[s1 * 6 + f2]);
        float2 v2 = __half22float2(xh2[s2 * 6 + f2]);
        float2 v3 = __half22float2(xh2[s3 * 6 + f2]);
        a0.x += v0.x; a0.y += v0.y;
        a1.x += v1.x; a1.y += v1.y;
        a2.x += v2.x; a2.y += v2.y;
        a3.x += v3.x; a3.y += v3.y;
    }
    for (; i < end; ++i) {
        float2 v = __half22float2(xh2[csr_src[i] * 6 + f2]);
        a0.x += v.x; a0.y += v.y;
    }
    float2 r;
    r.x = a0.x + a1.x + a2.x + a3.x;
    r.y = a0.y + a1.y + a2.y + a3.y;
    ((float2*)agg1)[n * 6 + f2] = r;   // agg1 padded to 12 floats/node
}

// h = relu(agg1/deg * W1l + x * W1r + b1) stored fp16; thread = (n, j<64)
__global__ void layer1_node_kernel(const float* __restrict__ x,
                                   const float* __restrict__ agg1,
                                   const int* __restrict__ deg_i,
                                   const float* __restrict__ W1l,
                                   const float* __restrict__ W1r,
                                   const float* __restrict__ b1,
                                   __half* __restrict__ hh) {
    int tid = blockIdx.x * blockDim.x + threadIdx.x;
    int n = tid >> 6;
    int j = tid & 63;
    if (n >= N_NODES) return;
    float invd = 1.0f / fmaxf((float)deg_i[n], 1.0f);
    float acc = b1[j];
    #pragma unroll
    for (int f = 0; f < F_IN; ++f) {
        float a = agg1[n * 12 + f] * invd;
        float xv = x[n * F_IN + f];
        acc += a * W1l[f * F_H + j] + xv * W1r[f * F_H + j];
    }
    hh[n * F_H + j] = __float2half(fmaxf(acc, 0.0f));
}

// ---------------- dual projection: p8 = fp8(h@W2l) [N,32]=3.2MB, r2 = h@W2r+b2 fp32 --
__global__ void proj2_dual_kernel(const __half2* __restrict__ hh2,
                                  const float* __restrict__ W2l,
                                  const float* __restrict__ W2r,
                                  const float* __restrict__ b2,
                                  unsigned char* __restrict__ p8,
                                  float* __restrict__ r2) {
    int tid = blockIdx.x * blockDim.x + threadIdx.x;
    int n = tid >> 5;
    int j = tid & 31;
    if (n >= N_NODES) return;
    const __half2* hrow = hh2 + n * 32;
    float accL = 0.0f, accR = 0.0f;
    #pragma unroll
    for (int k2 = 0; k2 < 32; ++k2) {
        float2 hv = __half22float2(hrow[k2]);
        accL += hv.x * W2l[(2 * k2) * F_E + j] + hv.y * W2l[(2 * k2 + 1) * F_E + j];
        accR += hv.x * W2r[(2 * k2) * F_E + j] + hv.y * W2r[(2 * k2 + 1) * F_E + j];
    }
    r2[n * F_E + j] = accR + b2[j];
    __hip_fp8_e4m3 q(accL);
    p8[n * F_E + j] = (unsigned char)q.__x;
}

// decode 4 packed fp8 e4m3 -> 4 floats
__device__ inline float4 fp8x4_to_f32(unsigned int w) {
    __hip_fp8_e4m3 a, b, c, d;
    a.__x = (__hip_fp8_storage_t)(w & 0xFF);
    b.__x = (__hip_fp8_storage_t)((w >> 8) & 0xFF);
    c.__x = (__hip_fp8_storage_t)((w >> 16) & 0xFF);
    d.__x = (__hip_fp8_storage_t)((w >> 24) & 0xFF);
    return make_float4((float)a, (float)b, (float)c, (float)d);
}

// ---------------- layer 2 fused: fp8 gather (L2-resident 3.2MB) + relu + logits ------
// 8 lanes/node; lane l owns features 4l..4l+3 (one uint = 4 fp8 per neighbor).
__global__ void layer2_fused_kernel(const int* __restrict__ csr_src,
                                    const int* __restrict__ offsets,
                                    const int* __restrict__ deg_i,
                                    const unsigned int* __restrict__ p8u,  // [N][8] uint
                                    const float* __restrict__ r2,
                                    const float* __restrict__ Wc,
                                    const float* __restrict__ bc,
                                    float* __restrict__ emb,
                                    float* __restrict__ logits) {
    int tid = blockIdx.x * blockDim.x + threadIdx.x;
    int n = tid >> 3;
    int l = tid & 7;
    if (n >= N_NODES) return;
    int start = offsets[n];
    int cnt = deg_i[n];
    int end = start + cnt;
    float ax = 0.f, ay = 0.f, az = 0.f, aw = 0.f;
    float bx = 0.f, by = 0.f, bz = 0.f, bw = 0.f;
    int i = start;
    for (; i + 4 <= end; i += 4) {
        int s0 = csr_src[i], s1 = csr_src[i + 1], s2 = csr_src[i + 2], s3 = csr_src[i + 3];
        unsigned int w0 = p8u[s0 * 8 + l];
        unsigned int w1 = p8u[s1 * 8 + l];
        unsigned int w2 = p8u[s2 * 8 + l];
        unsigned int w3 = p8u[s3 * 8 + l];
        float4 v0 = fp8x4_to_f32(w0);
        float4 v1 = fp8x4_to_f32(w1);
        float4 v2 = fp8x4_to_f32(w2);
        float4 v3 = fp8x4_to_f32(w3);
        ax += v0.x + v2.x; ay += v0.y + v2.y; az += v0.z + v2.z; aw += v0.w + v2.w;
        bx += v1.x + v3.x; by += v1.y + v3.y; bz += v1.z + v3.z; bw += v1.w + v3.w;
    }
    for (; i < end; ++i) {
        float4 v = fp8x4_to_f32(p8u[csr_src[i] * 8 + l]);
        ax += v.x; ay += v.y; az += v.z; aw += v.w;
    }
    float invd = 1.0f / fmaxf((float)cnt, 1.0f);
    const float* rrow = r2 + n * F_E + 4 * l;
    float4 e;
    e.x = fmaxf((ax + bx) * invd + rrow[0], 0.0f);
    e.y = fmaxf((ay + by) * invd + rrow[1], 0.0f);
    e.z = fmaxf((az + bz) * invd + rrow[2], 0.0f);
    e.w = fmaxf((aw + bw) * invd + rrow[3], 0.0f);
    ((float4*)emb)[n * 8 + l] = e;
    const float* wc = Wc + (4 * l) * 3;
    float c0 = e.x * wc[0] + e.y * wc[3] + e.z * wc[6] + e.w * wc[9];
    float c1 = e.x * wc[1] + e.y * wc[4] + e.z * wc[7] + e.w * wc[10];
    float c2 = e.x * wc[2] + e.y * wc[5] + e.z * wc[8] + e.w * wc[11];
    #pragma unroll
    for (int m = 1; m < 8; m <<= 1) {
        c0 += __shfl_xor(c0, m);
        c1 += __shfl_xor(c1, m);
        c2 += __shfl_xor(c2, m);
    }
    if (l == 0) {
        logits[n * 3 + 0] = c0 + bc[0];
        logits[n * 3 + 1] = c1 + bc[1];
        logits[n * 3 + 2] = c2 + bc[2];
    }
}

extern "C" void kernel_launch(void* const* d_in, const int* in_sizes, int n_in,
                              void* d_out, int out_size, void* d_ws, size_t ws_size,
                              hipStream_t stream) {
    const float* x   = (const float*)d_in[0];
    const int*   ei  = (const int*)d_in[1];
    const float* W1l = (const float*)d_in[2];
    const float* W1r = (const float*)d_in[3];
    const float* b1  = (const float*)d_in[4];
    const float* W2l = (const float*)d_in[5];
    const float* W2r = (const float*)d_in[6];
    const float* b2  = (const float*)d_in[7];
    const float* Wc  = (const float*)d_in[8];
    const float* bc  = (const float*)d_in[9];

    const int* src = ei;
    const int* dst = ei + E_EDGES;

    float* out    = (float*)d_out;
    float* logits = out;
    float* emb    = out + (size_t)N_NODES * 3;

    // ws layout (4B units), total ~53 MB:
    //   deg_i   : N
    //   offsets : N
    //   cursor  : 512
    //   csr_src : BUCKETS*CAP (3.60M)
    //   region1 : BUCKETS*CAP: pairs (binA..binB) -> hh 32N (layer1..proj2)
    //   r2      : 32N fp32
    //   p8      : 8N units ([N,32] fp8)
    //   xh      : 6N units (12N halves)
    //   agg1    : 12N floats
    int* ws_i     = (int*)d_ws;
    int* deg_i    = ws_i;
    int* offsets  = ws_i + N_NODES;
    int* cursor   = ws_i + 2 * N_NODES;
    int* csr_src  = cursor + 512;
    int* region1  = csr_src + (size_t)BUCKETS * CAP;
    unsigned int* pairs = (unsigned int*)region1;
    __half* hh    = (__half*)region1;                         // 64N halves (alias of pairs)
    int* base2    = region1 + (size_t)BUCKETS * CAP;
    float* r2     = (float*)base2;                            // 32N
    unsigned char* p8 = (unsigned char*)(base2 + (size_t)32 * N_NODES);  // 8N units
    __half* xh    = (__half*)(base2 + (size_t)40 * N_NODES);  // 6N units
    float* agg1   = (float*)(base2 + (size_t)46 * N_NODES);   // 12N

    hipMemsetAsync(cursor, 0, 512 * sizeof(int), stream);

    const int BS = 256;

    convert_x_kernel<<<(N_NODES * 12 + BS - 1) / BS, BS, 0, stream>>>(x, xh);
    binA_kernel<<<NWG_A, 1024, 0, stream>>>(src, dst, cursor, pairs);
    binB_kernel<<<BUCKETS, 512, 0, stream>>>(pairs, cursor, deg_i, offsets, csr_src);

    gather1_kernel<<<(N_NODES * 8 + BS - 1) / BS, BS, 0, stream>>>(
        csr_src, offsets, deg_i, (const __half2*)xh, agg1);
    layer1_node_kernel<<<(N_NODES * 64 + BS - 1) / BS, BS, 0, stream>>>(
        x, agg1, deg_i, W1l, W1r, b1, hh);
    proj2_dual_kernel<<<(N_NODES * 32 + BS - 1) / BS, BS, 0, stream>>>(
        (const __half2*)hh, W2l, W2r, b2, p8, r2);
    layer2_fused_kernel<<<(N_NODES * 8 + BS - 1) / BS, BS, 0, stream>>>(
        csr_src, offsets, deg_i, (const unsigned int*)p8, r2, Wc, bc, emb, logits);
}

// Round 11
// 276.574 us; speedup vs baseline: 4.1800x; 1.1224x over previous
//
#include <hip/hip_runtime.h>
#include <hip/hip_fp16.h>
#include <hip/hip_fp8.h>

#define N_NODES 100000
#define E_EDGES 3200000
#define F_IN 11
#define F_H 64
#define F_E 32

#define BUCKETS ((N_NODES + 255) >> 8)   // 391 coarse buckets (dst>>8)
#define CAP 9216                         // slack bucket capacity (mean ~8184, +11 sigma)
#define CHUNK_A 12288
#define NWG_A ((E_EDGES + CHUNK_A - 1) / CHUNK_A)  // 261

// ---------------- CSR construction (slack buckets, no counting pass) ----------------
// 1024-thread blocks: same chunk/run-length (write-amp ~2x) but 16 waves/CU.
__global__ void binA_kernel(const int* __restrict__ src,
                            const int* __restrict__ dst,
                            int* __restrict__ cursor,
                            unsigned int* __restrict__ pairs) {
    __shared__ int lh[BUCKETS];
    int t = threadIdx.x;
    for (int i = t; i < BUCKETS; i += 1024) lh[i] = 0;
    __syncthreads();
    int e0 = blockIdx.x * CHUNK_A;
    int e1 = min(e0 + CHUNK_A, E_EDGES);
    for (int i = e0 + t; i < e1; i += 1024)
        atomicAdd(&lh[dst[i] >> 8], 1);
    __syncthreads();
    for (int i = t; i < BUCKETS; i += 1024) {
        int c = lh[i];
        lh[i] = (c > 0) ? (i * CAP + atomicAdd(&cursor[i], c)) : 0;
    }
    __syncthreads();
    for (int i = e0 + t; i < e1; i += 1024) {
        int d = dst[i];
        int b = d >> 8;
        int pos = atomicAdd(&lh[b], 1);
        pairs[pos] = (unsigned int)src[i] | (((unsigned int)(d & 255)) << 17);
    }
}

// 512-thread blocks (scan portion uses first 256 threads; barriers are uniform).
__global__ void binB_kernel(const unsigned int* __restrict__ pairs,
                            const int* __restrict__ cursor,
                            int* __restrict__ deg_i,
                            int* __restrict__ offsets,
                            int* __restrict__ csr_src) {
    __shared__ int lhist[256];
    __shared__ int lscan[256];
    __shared__ int lcur[256];
    int b = blockIdx.x;
    int t = threadIdx.x;
    if (t < 256) lhist[t] = 0;
    __syncthreads();
    int start = b * CAP;
    int end = start + cursor[b];
    for (int i = start + t; i < end; i += 512)
        atomicAdd(&lhist[pairs[i] >> 17], 1);
    __syncthreads();
    int cnt = (t < 256) ? lhist[t] : 0;
    if (t < 256) lscan[t] = cnt;
    __syncthreads();
    int incl = cnt;
    for (int off = 1; off < 256; off <<= 1) {
        int tmp = (t < 256 && t >= off) ? lscan[t - off] : 0;
        __syncthreads();
        if (t < 256) {
            incl += tmp;
            lscan[t] = incl;
        }
        __syncthreads();
    }
    if (t < 256) {
        int ex = start + incl - cnt;  // offset within slack csr layout
        int node = (b << 8) + t;
        if (node < N_NODES) {
            deg_i[node] = cnt;
            offsets[node] = ex;
        }
        lcur[t] = ex;
    }
    __syncthreads();
    for (int i = start + t; i < end; i += 512) {
        unsigned int p = pairs[i];
        int pos = atomicAdd(&lcur[p >> 17], 1);
        csr_src[pos] = (int)(p & 0x1FFFFu);
    }
}

// ---------------- fp16 conversion of x ----------------
__global__ void convert_x_kernel(const float* __restrict__ x, __half* __restrict__ xh) {
    int tid = blockIdx.x * blockDim.x + threadIdx.x;
    if (tid >= N_NODES * 12) return;
    int n = tid / 12;
    int f = tid - n * 12;
    xh[tid] = __float2half((f < F_IN) ? x[n * F_IN + f] : 0.0f);
}

// ---------------- layer 1 ----------------

// gather via half2: 8 lanes/node, lanes 0..5 active (6 half2 = 12 halves/row)
__global__ void gather1_kernel(const int* __restrict__ csr_src,
                               const int* __restrict__ offsets,
                               const int* __restrict__ deg_i,
                               const __half2* __restrict__ xh2,
                               float* __restrict__ agg1) {
    int tid = blockIdx.x * blockDim.x + threadIdx.x;
    int n = tid >> 3;
    int f2 = tid & 7;
    if (n >= N_NODES || f2 >= 6) return;
    int start = offsets[n];
    int end = start + deg_i[n];
    float2 a0 = {0.f, 0.f}, a1 = {0.f, 0.f}, a2 = {0.f, 0.f}, a3 = {0.f, 0.f};
    int i = start;
    for (; i + 4 <= end; i += 4) {
        int s0 = csr_src[i], s1 = csr_src[i + 1], s2 = csr_src[i + 2], s3 = csr_src[i + 3];
        float2 v0 = __half22float2(xh2[s0 * 6 + f2]);
        float2 v1 = __half22float2(xh2[s1 * 6 + f2]);
        float2 v2 = __half22float2(xh2[s2 * 6 + f2]);
        float2 v3 = __half22float2(xh2[s3 * 6 + f2]);
        a0.x += v0.x; a0.y += v0.y;
        a1.x += v1.x; a1.y += v1.y;
        a2.x += v2.x; a2.y += v2.y;
        a3.x += v3.x; a3.y += v3.y;
    }
    for (; i < end; ++i) {
        float2 v = __half22float2(xh2[csr_src[i] * 6 + f2]);
        a0.x += v.x; a0.y += v.y;
    }
    float2 r;
    r.x = a0.x + a1.x + a2.x + a3.x;
    r.y = a0.y + a1.y + a2.y + a3.y;
    ((float2*)agg1)[n * 6 + f2] = r;   // agg1 padded to 12 floats/node
}

// h = relu(agg1/deg * W1l + x * W1r + b1) stored fp16; thread = (n, j<64)
__global__ void layer1_node_kernel(const float* __restrict__ x,
                                   const float* __restrict__ agg1,
                                   const int* __restrict__ deg_i,
                                   const float* __restrict__ W1l,
                                   const float* __restrict__ W1r,
                                   const float* __restrict__ b1,
                                   __half* __restrict__ hh) {
    int tid = blockIdx.x * blockDim.x + threadIdx.x;
    int n = tid >> 6;
    int j = tid & 63;
    if (n >= N_NODES) return;
    float invd = 1.0f / fmaxf((float)deg_i[n], 1.0f);
    float acc = b1[j];
    #pragma unroll
    for (int f = 0; f < F_IN; ++f) {
        float a = agg1[n * 12 + f] * invd;
        float xv = x[n * F_IN + f];
        acc += a * W1l[f * F_H + j] + xv * W1r[f * F_H + j];
    }
    hh[n * F_H + j] = __float2half(fmaxf(acc, 0.0f));
}

// ---------------- dual projection, 4-node register blocking ----------------
// thread = (group g of 4 nodes, j<32). Weights loaded once, reused for 4 nodes.
__global__ void proj2_dual_kernel(const __half2* __restrict__ hh2,
                                  const float* __restrict__ W2l,
                                  const float* __restrict__ W2r,
                                  const float* __restrict__ b2,
                                  unsigned char* __restrict__ p8,
                                  float* __restrict__ r2) {
    int tid = blockIdx.x * blockDim.x + threadIdx.x;
    int g = tid >> 5;
    int j = tid & 31;
    int n0 = g << 2;
    if (n0 >= N_NODES) return;
    const __half2* h0 = hh2 + (size_t)n0 * 32;
    float aL0 = 0.f, aL1 = 0.f, aL2 = 0.f, aL3 = 0.f;
    float aR0 = 0.f, aR1 = 0.f, aR2 = 0.f, aR3 = 0.f;
    #pragma unroll
    for (int k2 = 0; k2 < 32; ++k2) {
        float wLa = W2l[(2 * k2) * F_E + j];
        float wLb = W2l[(2 * k2 + 1) * F_E + j];
        float wRa = W2r[(2 * k2) * F_E + j];
        float wRb = W2r[(2 * k2 + 1) * F_E + j];
        float2 h0v = __half22float2(h0[k2]);
        float2 h1v = __half22float2(h0[32 + k2]);
        float2 h2v = __half22float2(h0[64 + k2]);
        float2 h3v = __half22float2(h0[96 + k2]);
        aL0 += h0v.x * wLa + h0v.y * wLb;  aR0 += h0v.x * wRa + h0v.y * wRb;
        aL1 += h1v.x * wLa + h1v.y * wLb;  aR1 += h1v.x * wRa + h1v.y * wRb;
        aL2 += h2v.x * wLa + h2v.y * wLb;  aR2 += h2v.x * wRa + h2v.y * wRb;
        aL3 += h3v.x * wLa + h3v.y * wLb;  aR3 += h3v.x * wRa + h3v.y * wRb;
    }
    float bb = b2[j];
    r2[(size_t)(n0 + 0) * F_E + j] = aR0 + bb;
    r2[(size_t)(n0 + 1) * F_E + j] = aR1 + bb;
    r2[(size_t)(n0 + 2) * F_E + j] = aR2 + bb;
    r2[(size_t)(n0 + 3) * F_E + j] = aR3 + bb;
    __hip_fp8_e4m3 q0(aL0), q1(aL1), q2(aL2), q3(aL3);
    p8[(size_t)(n0 + 0) * F_E + j] = (unsigned char)q0.__x;
    p8[(size_t)(n0 + 1) * F_E + j] = (unsigned char)q1.__x;
    p8[(size_t)(n0 + 2) * F_E + j] = (unsigned char)q2.__x;
    p8[(size_t)(n0 + 3) * F_E + j] = (unsigned char)q3.__x;
}

// decode 4 packed fp8 e4m3 -> 4 floats
__device__ inline float4 fp8x4_to_f32(unsigned int w) {
    __hip_fp8_e4m3 a, b, c, d;
    a.__x = (__hip_fp8_storage_t)(w & 0xFF);
    b.__x = (__hip_fp8_storage_t)((w >> 8) & 0xFF);
    c.__x = (__hip_fp8_storage_t)((w >> 16) & 0xFF);
    d.__x = (__hip_fp8_storage_t)((w >> 24) & 0xFF);
    return make_float4((float)a, (float)b, (float)c, (float)d);
}

// ---------------- layer 2 fused: fp8 gather (L2-resident 3.2MB) + relu + logits ------
// 8 lanes/node; lane l owns features 4l..4l+3 (one uint = 4 fp8 per neighbor).
__global__ void layer2_fused_kernel(const int* __restrict__ csr_src,
                                    const int* __restrict__ offsets,
                                    const int* __restrict__ deg_i,
                                    const unsigned int* __restrict__ p8u,  // [N][8] uint
                                    const float* __restrict__ r2,
                                    const float* __restrict__ Wc,
                                    const float* __restrict__ bc,
                                    float* __restrict__ emb,
                                    float* __restrict__ logits) {
    int tid = blockIdx.x * blockDim.x + threadIdx.x;
    int n = tid >> 3;
    int l = tid & 7;
    if (n >= N_NODES) return;
    int start = offsets[n];
    int cnt = deg_i[n];
    int end = start + cnt;
    float ax = 0.f, ay = 0.f, az = 0.f, aw = 0.f;
    float bx = 0.f, by = 0.f, bz = 0.f, bw = 0.f;
    int i = start;
    for (; i + 4 <= end; i += 4) {
        int s0 = csr_src[i], s1 = csr_src[i + 1], s2 = csr_src[i + 2], s3 = csr_src[i + 3];
        unsigned int w0 = p8u[s0 * 8 + l];
        unsigned int w1 = p8u[s1 * 8 + l];
        unsigned int w2 = p8u[s2 * 8 + l];
        unsigned int w3 = p8u[s3 * 8 + l];
        float4 v0 = fp8x4_to_f32(w0);
        float4 v1 = fp8x4_to_f32(w1);
        float4 v2 = fp8x4_to_f32(w2);
        float4 v3 = fp8x4_to_f32(w3);
        ax += v0.x + v2.x; ay += v0.y + v2.y; az += v0.z + v2.z; aw += v0.w + v2.w;
        bx += v1.x + v3.x; by += v1.y + v3.y; bz += v1.z + v3.z; bw += v1.w + v3.w;
    }
    for (; i < end; ++i) {
        float4 v = fp8x4_to_f32(p8u[csr_src[i] * 8 + l]);
        ax += v.x; ay += v.y; az += v.z; aw += v.w;
    }
    float invd = 1.0f / fmaxf((float)cnt, 1.0f);
    const float* rrow = r2 + n * F_E + 4 * l;
    float4 e;
    e.x = fmaxf((ax + bx) * invd + rrow[0], 0.0f);
    e.y = fmaxf((ay + by) * invd + rrow[1], 0.0f);
    e.z = fmaxf((az + bz) * invd + rrow[2], 0.0f);
    e.w = fmaxf((aw + bw) * invd + rrow[3], 0.0f);
    ((float4*)emb)[n * 8 + l] = e;
    const float* wc = Wc + (4 * l) * 3;
    float c0 = e.x * wc[0] + e.y * wc[3] + e.z * wc[6] + e.w * wc[9];
    float c1 = e.x * wc[1] + e.y * wc[4] + e.z * wc[7] + e.w * wc[10];
    float c2 = e.x * wc[2] + e.y * wc[5] + e.z * wc[8] + e.w * wc[11];
    #pragma unroll
    for (int m = 1; m < 8; m <<= 1) {
        c0 += __shfl_xor(c0, m);
        c1 += __shfl_xor(c1, m);
        c2 += __shfl_xor(c2, m);
    }
    if (l == 0) {
        logits[n * 3 + 0] = c0 + bc[0];
        logits[n * 3 + 1] = c1 + bc[1];
        logits[n * 3 + 2] = c2 + bc[2];
    }
}

extern "C" void kernel_launch(void* const* d_in, const int* in_sizes, int n_in,
                              void* d_out, int out_size, void* d_ws, size_t ws_size,
                              hipStream_t stream) {
    const float* x   = (const float*)d_in[0];
    const int*   ei  = (const int*)d_in[1];
    const float* W1l = (const float*)d_in[2];
    const float* W1r = (const float*)d_in[3];
    const float* b1  = (const float*)d_in[4];
    const float* W2l = (const float*)d_in[5];
    const float* W2r = (const float*)d_in[6];
    const float* b2  = (const float*)d_in[7];
    const float* Wc  = (const float*)d_in[8];
    const float* bc  = (const float*)d_in[9];

    const int* src = ei;
    const int* dst = ei + E_EDGES;

    float* out    = (float*)d_out;
    float* logits = out;
    float* emb    = out + (size_t)N_NODES * 3;

    // ws layout (4B units), total ~53 MB:
    //   deg_i   : N
    //   offsets : N
    //   cursor  : 512
    //   csr_src : BUCKETS*CAP (3.60M)
    //   region1 : BUCKETS*CAP: pairs (binA..binB) -> hh 32N (layer1..proj2)
    //   r2      : 32N fp32
    //   p8      : 8N units ([N,32] fp8)
    //   xh      : 6N units (12N halves)
    //   agg1    : 12N floats
    int* ws_i     = (int*)d_ws;
    int* deg_i    = ws_i;
    int* offsets  = ws_i + N_NODES;
    int* cursor   = ws_i + 2 * N_NODES;
    int* csr_src  = cursor + 512;
    int* region1  = csr_src + (size_t)BUCKETS * CAP;
    unsigned int* pairs = (unsigned int*)region1;
    __half* hh    = (__half*)region1;                         // 64N halves (alias of pairs)
    int* base2    = region1 + (size_t)BUCKETS * CAP;
    float* r2     = (float*)base2;                            // 32N
    unsigned char* p8 = (unsigned char*)(base2 + (size_t)32 * N_NODES);  // 8N units
    __half* xh    = (__half*)(base2 + (size_t)40 * N_NODES);  // 6N units
    float* agg1   = (float*)(base2 + (size_t)46 * N_NODES);   // 12N

    hipMemsetAsync(cursor, 0, 512 * sizeof(int), stream);

    const int BS = 256;

    convert_x_kernel<<<(N_NODES * 12 + BS - 1) / BS, BS, 0, stream>>>(x, xh);
    binA_kernel<<<NWG_A, 1024, 0, stream>>>(src, dst, cursor, pairs);
    binB_kernel<<<BUCKETS, 512, 0, stream>>>(pairs, cursor, deg_i, offsets, csr_src);

    gather1_kernel<<<(N_NODES * 8 + BS - 1) / BS, BS, 0, stream>>>(
        csr_src, offsets, deg_i, (const __half2*)xh, agg1);
    layer1_node_kernel<<<(N_NODES * 64 + BS - 1) / BS, BS, 0, stream>>>(
        x, agg1, deg_i, W1l, W1r, b1, hh);
    proj2_dual_kernel<<<((N_NODES / 4) * 32 + BS - 1) / BS, BS, 0, stream>>>(
        (const __half2*)hh, W2l, W2r, b2, p8, r2);
    layer2_fused_kernel<<<(N_NODES * 8 + BS - 1) / BS, BS, 0, stream>>>(
        csr_src, offsets, deg_i, (const unsigned int*)p8, r2, Wc, bc, emb, logits);
}

// Round 12
// 264.065 us; speedup vs baseline: 4.3780x; 1.0474x over previous
//
#include <hip/hip_runtime.h>
#include <hip/hip_fp16.h>
#include <hip/hip_fp8.h>

#define N_NODES 100000
#define E_EDGES 3200000
#define F_IN 11
#define F_H 64
#define F_E 32

#define BUCKETS ((N_NODES + 255) >> 8)   // 391 coarse buckets (dst>>8)
#define CAP 9216                         // slack bucket capacity (mean ~8184, +11 sigma)
#define CHUNK_A 12288
#define NWG_A ((E_EDGES + CHUNK_A - 1) / CHUNK_A)  // 261
#define EPT 12                            // edges per thread (CHUNK_A / 1024)

// ---------------- binA: LDS counting-sort -> coalesced global pair writes ----------
// 1024 threads. Edges held in registers between histogram and scatter (no re-read).
__global__ void binA_kernel(const int* __restrict__ src,
                            const int* __restrict__ dst,
                            int* __restrict__ cursor,
                            unsigned int* __restrict__ pairs) {
    __shared__ int lh[BUCKETS + 1];      // histogram
    __shared__ int lstart[BUCKETS + 1];  // local exclusive scan (+ total sentinel)
    __shared__ int lcur[BUCKETS];        // insertion cursors
    __shared__ int gbase[BUCKETS];       // global reserved base per bucket
    __shared__ unsigned int stage[CHUNK_A];
    int t = threadIdx.x;
    for (int i = t; i <= BUCKETS; i += 1024) lh[i] = 0;
    __syncthreads();

    int e0 = blockIdx.x * CHUNK_A;
    int e1 = min(e0 + CHUNK_A, E_EDGES);

    // phase 1: histogram + build pairs in registers
    unsigned int pv[EPT];
    int pb[EPT];
    int cnt = 0;
    for (int i = e0 + t; i < e1; i += 1024) {
        int d = dst[i];
        int b = d >> 8;
        pv[cnt] = (unsigned int)src[i] | (((unsigned int)(d & 255)) << 17);
        pb[cnt] = b;
        ++cnt;
        atomicAdd(&lh[b], 1);
    }
    __syncthreads();

    // phase 2a: inclusive scan of lh -> lstart (exclusive) using Hillis-Steele
    for (int i = t; i < BUCKETS; i += 1024) lstart[i] = lh[i];
    __syncthreads();
    for (int off = 1; off < 512; off <<= 1) {
        int v = 0;
        if (t < BUCKETS && t >= off) v = lstart[t - off];
        __syncthreads();
        if (t < BUCKETS && t >= off) lstart[t] += v;
        __syncthreads();
    }
    // convert inclusive -> exclusive, set sentinel, reserve global space
    int myIncl = (t < BUCKETS) ? lstart[t] : 0;
    int myCnt  = (t < BUCKETS) ? lh[t] : 0;
    __syncthreads();
    if (t < BUCKETS) {
        int ex = myIncl - myCnt;
        lstart[t] = ex;
        lcur[t] = ex;
        if (myCnt > 0) gbase[t] = t * CAP + atomicAdd(&cursor[t], myCnt);
    }
    if (t == 0) lstart[BUCKETS] = e1 - e0;
    __syncthreads();

    // phase 3: scatter into LDS stage (sorted by bucket)
    for (int k = 0; k < cnt; ++k) {
        int pos = atomicAdd(&lcur[pb[k]], 1);
        stage[pos] = pv[k];
    }
    __syncthreads();

    // phase 4: streamed write-out; consecutive threads -> consecutive addresses
    int total = e1 - e0;
    for (int i = t; i < total; i += 1024) {
        int lo = 0, hi = BUCKETS;  // invariant: lstart[lo] <= i < lstart[hi]
        while (hi - lo > 1) {
            int mid = (lo + hi) >> 1;
            if (lstart[mid] <= i) lo = mid; else hi = mid;
        }
        pairs[gbase[lo] + (i - lstart[lo])] = stage[i];
    }
}

// 512-thread blocks (scan portion uses first 256 threads; barriers are uniform).
__global__ void binB_kernel(const unsigned int* __restrict__ pairs,
                            const int* __restrict__ cursor,
                            int* __restrict__ deg_i,
                            int* __restrict__ offsets,
                            int* __restrict__ csr_src) {
    __shared__ int lhist[256];
    __shared__ int lscan[256];
    __shared__ int lcur[256];
    int b = blockIdx.x;
    int t = threadIdx.x;
    if (t < 256) lhist[t] = 0;
    __syncthreads();
    int start = b * CAP;
    int end = start + cursor[b];
    for (int i = start + t; i < end; i += 512)
        atomicAdd(&lhist[pairs[i] >> 17], 1);
    __syncthreads();
    int cnt = (t < 256) ? lhist[t] : 0;
    if (t < 256) lscan[t] = cnt;
    __syncthreads();
    int incl = cnt;
    for (int off = 1; off < 256; off <<= 1) {
        int tmp = (t < 256 && t >= off) ? lscan[t - off] : 0;
        __syncthreads();
        if (t < 256) {
            incl += tmp;
            lscan[t] = incl;
        }
        __syncthreads();
    }
    if (t < 256) {
        int ex = start + incl - cnt;  // offset within slack csr layout
        int node = (b << 8) + t;
        if (node < N_NODES) {
            deg_i[node] = cnt;
            offsets[node] = ex;
        }
        lcur[t] = ex;
    }
    __syncthreads();
    for (int i = start + t; i < end; i += 512) {
        unsigned int p = pairs[i];
        int pos = atomicAdd(&lcur[p >> 17], 1);
        csr_src[pos] = (int)(p & 0x1FFFFu);
    }
}

// ---------------- fp16 conversion of x ----------------
__global__ void convert_x_kernel(const float* __restrict__ x, __half* __restrict__ xh) {
    int tid = blockIdx.x * blockDim.x + threadIdx.x;
    if (tid >= N_NODES * 12) return;
    int n = tid / 12;
    int f = tid - n * 12;
    xh[tid] = __float2half((f < F_IN) ? x[n * F_IN + f] : 0.0f);
}

// ---------------- layer 1 ----------------

// gather via half2: 8 lanes/node, lanes 0..5 active (6 half2 = 12 halves/row)
__global__ void gather1_kernel(const int* __restrict__ csr_src,
                               const int* __restrict__ offsets,
                               const int* __restrict__ deg_i,
                               const __half2* __restrict__ xh2,
                               float* __restrict__ agg1) {
    int tid = blockIdx.x * blockDim.x + threadIdx.x;
    int n = tid >> 3;
    int f2 = tid & 7;
    if (n >= N_NODES || f2 >= 6) return;
    int start = offsets[n];
    int end = start + deg_i[n];
    float2 a0 = {0.f, 0.f}, a1 = {0.f, 0.f}, a2 = {0.f, 0.f}, a3 = {0.f, 0.f};
    int i = start;
    for (; i + 4 <= end; i += 4) {
        int s0 = csr_src[i], s1 = csr_src[i + 1], s2 = csr_src[i + 2], s3 = csr_src[i + 3];
        float2 v0 = __half22float2(xh2[s0 * 6 + f2]);
        float2 v1 = __half22float2(xh2[s1 * 6 + f2]);
        float2 v2 = __half22float2(xh2[s2 * 6 + f2]);
        float2 v3 = __half22float2(xh2[s3 * 6 + f2]);
        a0.x += v0.x; a0.y += v0.y;
        a1.x += v1.x; a1.y += v1.y;
        a2.x += v2.x; a2.y += v2.y;
        a3.x += v3.x; a3.y += v3.y;
    }
    for (; i < end; ++i) {
        float2 v = __half22float2(xh2[csr_src[i] * 6 + f2]);
        a0.x += v.x; a0.y += v.y;
    }
    float2 r;
    r.x = a0.x + a1.x + a2.x + a3.x;
    r.y = a0.y + a1.y + a2.y + a3.y;
    ((float2*)agg1)[n * 6 + f2] = r;   // agg1 padded to 12 floats/node
}

// h = relu(agg1/deg * W1l + x * W1r + b1) stored fp16; thread = (n, j<64)
__global__ void layer1_node_kernel(const float* __restrict__ x,
                                   const float* __restrict__ agg1,
                                   const int* __restrict__ deg_i,
                                   const float* __restrict__ W1l,
                                   const float* __restrict__ W1r,
                                   const float* __restrict__ b1,
                                   __half* __restrict__ hh) {
    int tid = blockIdx.x * blockDim.x + threadIdx.x;
    int n = tid >> 6;
    int j = tid & 63;
    if (n >= N_NODES) return;
    float invd = 1.0f / fmaxf((float)deg_i[n], 1.0f);
    float acc = b1[j];
    #pragma unroll
    for (int f = 0; f < F_IN; ++f) {
        float a = agg1[n * 12 + f] * invd;
        float xv = x[n * F_IN + f];
        acc += a * W1l[f * F_H + j] + xv * W1r[f * F_H + j];
    }
    hh[n * F_H + j] = __float2half(fmaxf(acc, 0.0f));
}

// ---------------- dual projection, 4-node register blocking ----------------
__global__ void proj2_dual_kernel(const __half2* __restrict__ hh2,
                                  const float* __restrict__ W2l,
                                  const float* __restrict__ W2r,
                                  const float* __restrict__ b2,
                                  unsigned char* __restrict__ p8,
                                  float* __restrict__ r2) {
    int tid = blockIdx.x * blockDim.x + threadIdx.x;
    int g = tid >> 5;
    int j = tid & 31;
    int n0 = g << 2;
    if (n0 >= N_NODES) return;
    const __half2* h0 = hh2 + (size_t)n0 * 32;
    float aL0 = 0.f, aL1 = 0.f, aL2 = 0.f, aL3 = 0.f;
    float aR0 = 0.f, aR1 = 0.f, aR2 = 0.f, aR3 = 0.f;
    #pragma unroll
    for (int k2 = 0; k2 < 32; ++k2) {
        float wLa = W2l[(2 * k2) * F_E + j];
        float wLb = W2l[(2 * k2 + 1) * F_E + j];
        float wRa = W2r[(2 * k2) * F_E + j];
        float wRb = W2r[(2 * k2 + 1) * F_E + j];
        float2 h0v = __half22float2(h0[k2]);
        float2 h1v = __half22float2(h0[32 + k2]);
        float2 h2v = __half22float2(h0[64 + k2]);
        float2 h3v = __half22float2(h0[96 + k2]);
        aL0 += h0v.x * wLa + h0v.y * wLb;  aR0 += h0v.x * wRa + h0v.y * wRb;
        aL1 += h1v.x * wLa + h1v.y * wLb;  aR1 += h1v.x * wRa + h1v.y * wRb;
        aL2 += h2v.x * wLa + h2v.y * wLb;  aR2 += h2v.x * wRa + h2v.y * wRb;
        aL3 += h3v.x * wLa + h3v.y * wLb;  aR3 += h3v.x * wRa + h3v.y * wRb;
    }
    float bb = b2[j];
    r2[(size_t)(n0 + 0) * F_E + j] = aR0 + bb;
    r2[(size_t)(n0 + 1) * F_E + j] = aR1 + bb;
    r2[(size_t)(n0 + 2) * F_E + j] = aR2 + bb;
    r2[(size_t)(n0 + 3) * F_E + j] = aR3 + bb;
    __hip_fp8_e4m3 q0(aL0), q1(aL1), q2(aL2), q3(aL3);
    p8[(size_t)(n0 + 0) * F_E + j] = (unsigned char)q0.__x;
    p8[(size_t)(n0 + 1) * F_E + j] = (unsigned char)q1.__x;
    p8[(size_t)(n0 + 2) * F_E + j] = (unsigned char)q2.__x;
    p8[(size_t)(n0 + 3) * F_E + j] = (unsigned char)q3.__x;
}

// decode 4 packed fp8 e4m3 -> 4 floats
__device__ inline float4 fp8x4_to_f32(unsigned int w) {
    __hip_fp8_e4m3 a, b, c, d;
    a.__x = (__hip_fp8_storage_t)(w & 0xFF);
    b.__x = (__hip_fp8_storage_t)((w >> 8) & 0xFF);
    c.__x = (__hip_fp8_storage_t)((w >> 16) & 0xFF);
    d.__x = (__hip_fp8_storage_t)((w >> 24) & 0xFF);
    return make_float4((float)a, (float)b, (float)c, (float)d);
}

// ---------------- layer 2 fused: fp8 gather (L2-resident 3.2MB) + relu + logits ------
__global__ void layer2_fused_kernel(const int* __restrict__ csr_src,
                                    const int* __restrict__ offsets,
                                    const int* __restrict__ deg_i,
                                    const unsigned int* __restrict__ p8u,  // [N][8] uint
                                    const float* __restrict__ r2,
                                    const float* __restrict__ Wc,
                                    const float* __restrict__ bc,
                                    float* __restrict__ emb,
                                    float* __restrict__ logits) {
    int tid = blockIdx.x * blockDim.x + threadIdx.x;
    int n = tid >> 3;
    int l = tid & 7;
    if (n >= N_NODES) return;
    int start = offsets[n];
    int cnt = deg_i[n];
    int end = start + cnt;
    float ax = 0.f, ay = 0.f, az = 0.f, aw = 0.f;
    float bx = 0.f, by = 0.f, bz = 0.f, bw = 0.f;
    int i = start;
    for (; i + 4 <= end; i += 4) {
        int s0 = csr_src[i], s1 = csr_src[i + 1], s2 = csr_src[i + 2], s3 = csr_src[i + 3];
        unsigned int w0 = p8u[s0 * 8 + l];
        unsigned int w1 = p8u[s1 * 8 + l];
        unsigned int w2 = p8u[s2 * 8 + l];
        unsigned int w3 = p8u[s3 * 8 + l];
        float4 v0 = fp8x4_to_f32(w0);
        float4 v1 = fp8x4_to_f32(w1);
        float4 v2 = fp8x4_to_f32(w2);
        float4 v3 = fp8x4_to_f32(w3);
        ax += v0.x + v2.x; ay += v0.y + v2.y; az += v0.z + v2.z; aw += v0.w + v2.w;
        bx += v1.x + v3.x; by += v1.y + v3.y; bz += v1.z + v3.z; bw += v1.w + v3.w;
    }
    for (; i < end; ++i) {
        float4 v = fp8x4_to_f32(p8u[csr_src[i] * 8 + l]);
        ax += v.x; ay += v.y; az += v.z; aw += v.w;
    }
    float invd = 1.0f / fmaxf((float)cnt, 1.0f);
    const float* rrow = r2 + n * F_E + 4 * l;
    float4 e;
    e.x = fmaxf((ax + bx) * invd + rrow[0], 0.0f);
    e.y = fmaxf((ay + by) * invd + rrow[1], 0.0f);
    e.z = fmaxf((az + bz) * invd + rrow[2], 0.0f);
    e.w = fmaxf((aw + bw) * invd + rrow[3], 0.0f);
    ((float4*)emb)[n * 8 + l] = e;
    const float* wc = Wc + (4 * l) * 3;
    float c0 = e.x * wc[0] + e.y * wc[3] + e.z * wc[6] + e.w * wc[9];
    float c1 = e.x * wc[1] + e.y * wc[4] + e.z * wc[7] + e.w * wc[10];
    float c2 = e.x * wc[2] + e.y * wc[5] + e.z * wc[8] + e.w * wc[11];
    #pragma unroll
    for (int m = 1; m < 8; m <<= 1) {
        c0 += __shfl_xor(c0, m);
        c1 += __shfl_xor(c1, m);
        c2 += __shfl_xor(c2, m);
    }
    if (l == 0) {
        logits[n * 3 + 0] = c0 + bc[0];
        logits[n * 3 + 1] = c1 + bc[1];
        logits[n * 3 + 2] = c2 + bc[2];
    }
}

extern "C" void kernel_launch(void* const* d_in, const int* in_sizes, int n_in,
                              void* d_out, int out_size, void* d_ws, size_t ws_size,
                              hipStream_t stream) {
    const float* x   = (const float*)d_in[0];
    const int*   ei  = (const int*)d_in[1];
    const float* W1l = (const float*)d_in[2];
    const float* W1r = (const float*)d_in[3];
    const float* b1  = (const float*)d_in[4];
    const float* W2l = (const float*)d_in[5];
    const float* W2r = (const float*)d_in[6];
    const float* b2  = (const float*)d_in[7];
    const float* Wc  = (const float*)d_in[8];
    const float* bc  = (const float*)d_in[9];

    const int* src = ei;
    const int* dst = ei + E_EDGES;

    float* out    = (float*)d_out;
    float* logits = out;
    float* emb    = out + (size_t)N_NODES * 3;

    // ws layout (4B units), total ~53 MB:
    //   deg_i   : N
    //   offsets : N
    //   cursor  : 512
    //   csr_src : BUCKETS*CAP (3.60M)
    //   region1 : BUCKETS*CAP: pairs (binA..binB) -> hh 32N (layer1..proj2)
    //   r2      : 32N fp32
    //   p8      : 8N units ([N,32] fp8)
    //   xh      : 6N units (12N halves)
    //   agg1    : 12N floats
    int* ws_i     = (int*)d_ws;
    int* deg_i    = ws_i;
    int* offsets  = ws_i + N_NODES;
    int* cursor   = ws_i + 2 * N_NODES;
    int* csr_src  = cursor + 512;
    int* region1  = csr_src + (size_t)BUCKETS * CAP;
    unsigned int* pairs = (unsigned int*)region1;
    __half* hh    = (__half*)region1;                         // 64N halves (alias of pairs)
    int* base2    = region1 + (size_t)BUCKETS * CAP;
    float* r2     = (float*)base2;                            // 32N
    unsigned char* p8 = (unsigned char*)(base2 + (size_t)32 * N_NODES);  // 8N units
    __half* xh    = (__half*)(base2 + (size_t)40 * N_NODES);  // 6N units
    float* agg1   = (float*)(base2 + (size_t)46 * N_NODES);   // 12N

    hipMemsetAsync(cursor, 0, 512 * sizeof(int), stream);

    const int BS = 256;

    convert_x_kernel<<<(N_NODES * 12 + BS - 1) / BS, BS, 0, stream>>>(x, xh);
    binA_kernel<<<NWG_A, 1024, 0, stream>>>(src, dst, cursor, pairs);
    binB_kernel<<<BUCKETS, 512, 0, stream>>>(pairs, cursor, deg_i, offsets, csr_src);

    gather1_kernel<<<(N_NODES * 8 + BS - 1) / BS, BS, 0, stream>>>(
        csr_src, offsets, deg_i, (const __half2*)xh, agg1);
    layer1_node_kernel<<<(N_NODES * 64 + BS - 1) / BS, BS, 0, stream>>>(
        x, agg1, deg_i, W1l, W1r, b1, hh);
    proj2_dual_kernel<<<((N_NODES / 4) * 32 + BS - 1) / BS, BS, 0, stream>>>(
        (const __half2*)hh, W2l, W2r, b2, p8, r2);
    layer2_fused_kernel<<<(N_NODES * 8 + BS - 1) / BS, BS, 0, stream>>>(
        csr_src, offsets, deg_i, (const unsigned int*)p8, r2, Wc, bc, emb, logits);
}

// Round 13
// 229.478 us; speedup vs baseline: 5.0379x; 1.1507x over previous
//
#include <hip/hip_runtime.h>
#include <hip/hip_fp16.h>
#include <hip/hip_fp8.h>

#define N_NODES 100000
#define E_EDGES 3200000
#define F_IN 11
#define F_H 64
#define F_E 32

#define BUCKETS ((N_NODES + 255) >> 8)   // 391 coarse buckets (dst>>8)
#define CAP 9216                         // slack bucket capacity (mean ~8184, +11 sigma)
#define CHUNK_A 12288
#define NWG_A ((E_EDGES + CHUNK_A - 1) / CHUNK_A)  // 261
#define EPT 12                           // binA edges per thread (CHUNK_A / 1024)
#define EPT_B ((CAP + 511) / 512)        // binB pairs per thread (18)

// ---------------- binA: LDS counting-sort -> coalesced global pair writes ----------
__global__ void binA_kernel(const int* __restrict__ src,
                            const int* __restrict__ dst,
                            int* __restrict__ cursor,
                            unsigned int* __restrict__ pairs) {
    __shared__ int lh[BUCKETS + 1];
    __shared__ int lstart[BUCKETS + 1];
    __shared__ int lcur[BUCKETS];
    __shared__ int gbase[BUCKETS];
    __shared__ unsigned int stage[CHUNK_A];
    int t = threadIdx.x;
    for (int i = t; i <= BUCKETS; i += 1024) lh[i] = 0;
    __syncthreads();

    int e0 = blockIdx.x * CHUNK_A;
    int e1 = min(e0 + CHUNK_A, E_EDGES);

    unsigned int pv[EPT];
    int pb[EPT];
    int cnt = 0;
    for (int i = e0 + t; i < e1; i += 1024) {
        int d = dst[i];
        int b = d >> 8;
        pv[cnt] = (unsigned int)src[i] | (((unsigned int)(d & 255)) << 17);
        pb[cnt] = b;
        ++cnt;
        atomicAdd(&lh[b], 1);
    }
    __syncthreads();

    for (int i = t; i < BUCKETS; i += 1024) lstart[i] = lh[i];
    __syncthreads();
    for (int off = 1; off < 512; off <<= 1) {
        int v = 0;
        if (t < BUCKETS && t >= off) v = lstart[t - off];
        __syncthreads();
        if (t < BUCKETS && t >= off) lstart[t] += v;
        __syncthreads();
    }
    int myIncl = (t < BUCKETS) ? lstart[t] : 0;
    int myCnt  = (t < BUCKETS) ? lh[t] : 0;
    __syncthreads();
    if (t < BUCKETS) {
        int ex = myIncl - myCnt;
        lstart[t] = ex;
        lcur[t] = ex;
        if (myCnt > 0) gbase[t] = t * CAP + atomicAdd(&cursor[t], myCnt);
    }
    if (t == 0) lstart[BUCKETS] = e1 - e0;
    __syncthreads();

    for (int k = 0; k < cnt; ++k) {
        int pos = atomicAdd(&lcur[pb[k]], 1);
        stage[pos] = pv[k];
    }
    __syncthreads();

    int total = e1 - e0;
    for (int i = t; i < total; i += 1024) {
        int lo = 0, hi = BUCKETS;
        while (hi - lo > 1) {
            int mid = (lo + hi) >> 1;
            if (lstart[mid] <= i) lo = mid; else hi = mid;
        }
        pairs[gbase[lo] + (i - lstart[lo])] = stage[i];
    }
}

// ---------------- binB: single pairs read, LDS sort, coalesced csr write ----------
__global__ __launch_bounds__(512) void binB_kernel(const unsigned int* __restrict__ pairs,
                                                   const int* __restrict__ cursor,
                                                   int* __restrict__ deg_i,
                                                   int* __restrict__ offsets,
                                                   int* __restrict__ csr_src) {
    __shared__ int lhist[256];
    __shared__ int lscan[256];
    __shared__ int lcur[256];
    __shared__ unsigned int stage[CAP];
    int b = blockIdx.x;
    int t = threadIdx.x;
    if (t < 256) lhist[t] = 0;
    __syncthreads();
    int start = b * CAP;
    int cntAll = cursor[b];
    unsigned int pv[EPT_B];
    int c = 0;
    for (int i = t; i < cntAll; i += 512) {
        unsigned int p = pairs[start + i];
        pv[c++] = p;
        atomicAdd(&lhist[p >> 17], 1);
    }
    __syncthreads();
    int cnt = (t < 256) ? lhist[t] : 0;
    if (t < 256) lscan[t] = cnt;
    __syncthreads();
    int incl = cnt;
    for (int off = 1; off < 256; off <<= 1) {
        int tmp = (t < 256 && t >= off) ? lscan[t - off] : 0;
        __syncthreads();
        if (t < 256) {
            incl += tmp;
            lscan[t] = incl;
        }
        __syncthreads();
    }
    if (t < 256) {
        int ex = incl - cnt;  // local exclusive offset within bucket
        int node = (b << 8) + t;
        if (node < N_NODES) {
            deg_i[node] = cnt;
            offsets[node] = start + ex;
        }
        lcur[t] = ex;
    }
    __syncthreads();
    for (int k = 0; k < c; ++k) {
        int pos = atomicAdd(&lcur[pv[k] >> 17], 1);
        stage[pos] = pv[k] & 0x1FFFFu;
    }
    __syncthreads();
    for (int i = t; i < cntAll; i += 512)
        csr_src[start + i] = (int)stage[i];
}

// ---------------- fp16 conversion of x ----------------
__global__ void convert_x_kernel(const float* __restrict__ x, __half* __restrict__ xh) {
    int tid = blockIdx.x * blockDim.x + threadIdx.x;
    if (tid >= N_NODES * 12) return;
    int n = tid / 12;
    int f = tid - n * 12;
    xh[tid] = __float2half((f < F_IN) ? x[n * F_IN + f] : 0.0f);
}

// ---------------- layer 1 gather (unchanged) ----------------
__global__ void gather1_kernel(const int* __restrict__ csr_src,
                               const int* __restrict__ offsets,
                               const int* __restrict__ deg_i,
                               const __half2* __restrict__ xh2,
                               float* __restrict__ agg1) {
    int tid = blockIdx.x * blockDim.x + threadIdx.x;
    int n = tid >> 3;
    int f2 = tid & 7;
    if (n >= N_NODES || f2 >= 6) return;
    int start = offsets[n];
    int end = start + deg_i[n];
    float2 a0 = {0.f, 0.f}, a1 = {0.f, 0.f}, a2 = {0.f, 0.f}, a3 = {0.f, 0.f};
    int i = start;
    for (; i + 4 <= end; i += 4) {
        int s0 = csr_src[i], s1 = csr_src[i + 1], s2 = csr_src[i + 2], s3 = csr_src[i + 3];
        float2 v0 = __half22float2(xh2[s0 * 6 + f2]);
        float2 v1 = __half22float2(xh2[s1 * 6 + f2]);
        float2 v2 = __half22float2(xh2[s2 * 6 + f2]);
        float2 v3 = __half22float2(xh2[s3 * 6 + f2]);
        a0.x += v0.x; a0.y += v0.y;
        a1.x += v1.x; a1.y += v1.y;
        a2.x += v2.x; a2.y += v2.y;
        a3.x += v3.x; a3.y += v3.y;
    }
    for (; i < end; ++i) {
        float2 v = __half22float2(xh2[csr_src[i] * 6 + f2]);
        a0.x += v.x; a0.y += v.y;
    }
    float2 r;
    r.x = a0.x + a1.x + a2.x + a3.x;
    r.y = a0.y + a1.y + a2.y + a3.y;
    ((float2*)agg1)[n * 6 + f2] = r;
}

// ---------------- fused layer1 + dual projection ----------------
// Block = 16 nodes, 256 threads.
// Phase A: thread (node_local = t>>4, jq = t&15) computes h[j=4jq..4jq+3] -> LDS fp32.
// Phase B: thread (g = t>>6, lane = t&63: jj = lane&31, side = lane>>5) does the
//          4-node register-blocked dot over LDS h; side 0 -> p8 (fp8), side 1 -> r2.
__global__ void layer1_proj_kernel(const float* __restrict__ x,
                                   const float* __restrict__ agg1,
                                   const int* __restrict__ deg_i,
                                   const float* __restrict__ W1l,
                                   const float* __restrict__ W1r,
                                   const float* __restrict__ b1,
                                   const float* __restrict__ W2l,
                                   const float* __restrict__ W2r,
                                   const float* __restrict__ b2,
                                   unsigned char* __restrict__ p8,
                                   float* __restrict__ r2) {
    __shared__ float lh[16][64];
    int t = threadIdx.x;
    int n0 = blockIdx.x * 16;
    {
        int nl = t >> 4;
        int n = n0 + nl;
        int jq = t & 15;
        float invd = 1.0f / fmaxf((float)deg_i[n], 1.0f);
        float a[F_IN], xv[F_IN];
        #pragma unroll
        for (int f = 0; f < F_IN; ++f) {
            a[f] = agg1[n * 12 + f] * invd;
            xv[f] = x[n * F_IN + f];
        }
        #pragma unroll
        for (int i = 0; i < 4; ++i) {
            int j = jq * 4 + i;
            float acc = b1[j];
            #pragma unroll
            for (int f = 0; f < F_IN; ++f)
                acc += a[f] * W1l[f * F_H + j] + xv[f] * W1r[f * F_H + j];
            lh[nl][j] = fmaxf(acc, 0.0f);
        }
    }
    __syncthreads();
    {
        int g = t >> 6;         // 4 groups of 4 nodes
        int lane = t & 63;
        int jj = lane & 31;
        int side = lane >> 5;
        const float* W = side ? W2r : W2l;
        int nb = g * 4;
        float a0 = 0.f, a1 = 0.f, a2 = 0.f, a3 = 0.f;
        #pragma unroll
        for (int k = 0; k < F_H; ++k) {
            float w = W[k * F_E + jj];
            a0 += lh[nb + 0][k] * w;
            a1 += lh[nb + 1][k] * w;
            a2 += lh[nb + 2][k] * w;
            a3 += lh[nb + 3][k] * w;
        }
        size_t base = (size_t)(n0 + nb) * F_E + jj;
        if (side) {
            float bb = b2[jj];
            r2[base]            = a0 + bb;
            r2[base + F_E]      = a1 + bb;
            r2[base + 2 * F_E]  = a2 + bb;
            r2[base + 3 * F_E]  = a3 + bb;
        } else {
            __hip_fp8_e4m3 q0(a0), q1(a1), q2(a2), q3(a3);
            p8[base]           = (unsigned char)q0.__x;
            p8[base + F_E]     = (unsigned char)q1.__x;
            p8[base + 2 * F_E] = (unsigned char)q2.__x;
            p8[base + 3 * F_E] = (unsigned char)q3.__x;
        }
    }
}

// decode 4 packed fp8 e4m3 -> 4 floats
__device__ inline float4 fp8x4_to_f32(unsigned int w) {
    __hip_fp8_e4m3 a, b, c, d;
    a.__x = (__hip_fp8_storage_t)(w & 0xFF);
    b.__x = (__hip_fp8_storage_t)((w >> 8) & 0xFF);
    c.__x = (__hip_fp8_storage_t)((w >> 16) & 0xFF);
    d.__x = (__hip_fp8_storage_t)((w >> 24) & 0xFF);
    return make_float4((float)a, (float)b, (float)c, (float)d);
}

// ---------------- layer 2 fused: fp8 gather (L2-resident 3.2MB) + relu + logits ------
__global__ void layer2_fused_kernel(const int* __restrict__ csr_src,
                                    const int* __restrict__ offsets,
                                    const int* __restrict__ deg_i,
                                    const unsigned int* __restrict__ p8u,  // [N][8] uint
                                    const float* __restrict__ r2,
                                    const float* __restrict__ Wc,
                                    const float* __restrict__ bc,
                                    float* __restrict__ emb,
                                    float* __restrict__ logits) {
    int tid = blockIdx.x * blockDim.x + threadIdx.x;
    int n = tid >> 3;
    int l = tid & 7;
    if (n >= N_NODES) return;
    int start = offsets[n];
    int cnt = deg_i[n];
    int end = start + cnt;
    float ax = 0.f, ay = 0.f, az = 0.f, aw = 0.f;
    float bx = 0.f, by = 0.f, bz = 0.f, bw = 0.f;
    int i = start;
    for (; i + 4 <= end; i += 4) {
        int s0 = csr_src[i], s1 = csr_src[i + 1], s2 = csr_src[i + 2], s3 = csr_src[i + 3];
        unsigned int w0 = p8u[s0 * 8 + l];
        unsigned int w1 = p8u[s1 * 8 + l];
        unsigned int w2 = p8u[s2 * 8 + l];
        unsigned int w3 = p8u[s3 * 8 + l];
        float4 v0 = fp8x4_to_f32(w0);
        float4 v1 = fp8x4_to_f32(w1);
        float4 v2 = fp8x4_to_f32(w2);
        float4 v3 = fp8x4_to_f32(w3);
        ax += v0.x + v2.x; ay += v0.y + v2.y; az += v0.z + v2.z; aw += v0.w + v2.w;
        bx += v1.x + v3.x; by += v1.y + v3.y; bz += v1.z + v3.z; bw += v1.w + v3.w;
    }
    for (; i < end; ++i) {
        float4 v = fp8x4_to_f32(p8u[csr_src[i] * 8 + l]);
        ax += v.x; ay += v.y; az += v.z; aw += v.w;
    }
    float invd = 1.0f / fmaxf((float)cnt, 1.0f);
    const float* rrow = r2 + n * F_E + 4 * l;
    float4 e;
    e.x = fmaxf((ax + bx) * invd + rrow[0], 0.0f);
    e.y = fmaxf((ay + by) * invd + rrow[1], 0.0f);
    e.z = fmaxf((az + bz) * invd + rrow[2], 0.0f);
    e.w = fmaxf((aw + bw) * invd + rrow[3], 0.0f);
    ((float4*)emb)[n * 8 + l] = e;
    const float* wc = Wc + (4 * l) * 3;
    float c0 = e.x * wc[0] + e.y * wc[3] + e.z * wc[6] + e.w * wc[9];
    float c1 = e.x * wc[1] + e.y * wc[4] + e.z * wc[7] + e.w * wc[10];
    float c2 = e.x * wc[2] + e.y * wc[5] + e.z * wc[8] + e.w * wc[11];
    #pragma unroll
    for (int m = 1; m < 8; m <<= 1) {
        c0 += __shfl_xor(c0, m);
        c1 += __shfl_xor(c1, m);
        c2 += __shfl_xor(c2, m);
    }
    if (l == 0) {
        logits[n * 3 + 0] = c0 + bc[0];
        logits[n * 3 + 1] = c1 + bc[1];
        logits[n * 3 + 2] = c2 + bc[2];
    }
}

extern "C" void kernel_launch(void* const* d_in, const int* in_sizes, int n_in,
                              void* d_out, int out_size, void* d_ws, size_t ws_size,
                              hipStream_t stream) {
    const float* x   = (const float*)d_in[0];
    const int*   ei  = (const int*)d_in[1];
    const float* W1l = (const float*)d_in[2];
    const float* W1r = (const float*)d_in[3];
    const float* b1  = (const float*)d_in[4];
    const float* W2l = (const float*)d_in[5];
    const float* W2r = (const float*)d_in[6];
    const float* b2  = (const float*)d_in[7];
    const float* Wc  = (const float*)d_in[8];
    const float* bc  = (const float*)d_in[9];

    const int* src = ei;
    const int* dst = ei + E_EDGES;

    float* out    = (float*)d_out;
    float* logits = out;
    float* emb    = out + (size_t)N_NODES * 3;

    // ws layout (4B units):
    //   deg_i   : N
    //   offsets : N
    //   cursor  : 512
    //   csr_src : BUCKETS*CAP (3.60M)
    //   pairs   : BUCKETS*CAP (dead after binB)
    //   r2      : 32N fp32
    //   p8      : 8N units ([N,32] fp8)
    //   xh      : 6N units (12N halves)
    //   agg1    : 12N floats
    int* ws_i     = (int*)d_ws;
    int* deg_i    = ws_i;
    int* offsets  = ws_i + N_NODES;
    int* cursor   = ws_i + 2 * N_NODES;
    int* csr_src  = cursor + 512;
    int* region1  = csr_src + (size_t)BUCKETS * CAP;
    unsigned int* pairs = (unsigned int*)region1;
    int* base2    = region1 + (size_t)BUCKETS * CAP;
    float* r2     = (float*)base2;                            // 32N
    unsigned char* p8 = (unsigned char*)(base2 + (size_t)32 * N_NODES);  // 8N units
    __half* xh    = (__half*)(base2 + (size_t)40 * N_NODES);  // 6N units
    float* agg1   = (float*)(base2 + (size_t)46 * N_NODES);   // 12N

    hipMemsetAsync(cursor, 0, 512 * sizeof(int), stream);

    const int BS = 256;

    convert_x_kernel<<<(N_NODES * 12 + BS - 1) / BS, BS, 0, stream>>>(x, xh);
    binA_kernel<<<NWG_A, 1024, 0, stream>>>(src, dst, cursor, pairs);
    binB_kernel<<<BUCKETS, 512, 0, stream>>>(pairs, cursor, deg_i, offsets, csr_src);

    gather1_kernel<<<(N_NODES * 8 + BS - 1) / BS, BS, 0, stream>>>(
        csr_src, offsets, deg_i, (const __half2*)xh, agg1);
    layer1_proj_kernel<<<N_NODES / 16, BS, 0, stream>>>(
        x, agg1, deg_i, W1l, W1r, b1, W2l, W2r, b2, p8, r2);
    layer2_fused_kernel<<<(N_NODES * 8 + BS - 1) / BS, BS, 0, stream>>>(
        csr_src, offsets, deg_i, (const unsigned int*)p8, r2, Wc, bc, emb, logits);
}

// Round 14
// 225.406 us; speedup vs baseline: 5.1289x; 1.0181x over previous
//
#include <hip/hip_runtime.h>
#include <hip/hip_fp16.h>
#include <hip/hip_fp8.h>

#define N_NODES 100000
#define E_EDGES 3200000
#define F_IN 11
#define F_H 64
#define F_E 32

#define BUCKETS ((N_NODES + 255) >> 8)   // 391 coarse buckets (dst>>8)
#define CAP 9216                         // slack bucket capacity (mean ~8184, +11 sigma)
#define CHUNK_A 12288
#define NWG_A ((E_EDGES + CHUNK_A - 1) / CHUNK_A)  // 261
#define EPT 12                           // binA edges per thread (CHUNK_A / 1024)
#define EPT_B ((CAP + 511) / 512)        // binB pairs per thread (18)

typedef __attribute__((ext_vector_type(8))) _Float16 f16x8;
typedef __attribute__((ext_vector_type(4))) float f32x4;

// ---------------- binA: LDS counting-sort -> coalesced global pair writes ----------
__global__ void binA_kernel(const int* __restrict__ src,
                            const int* __restrict__ dst,
                            int* __restrict__ cursor,
                            unsigned int* __restrict__ pairs) {
    __shared__ int lh[BUCKETS + 1];
    __shared__ int lstart[BUCKETS + 1];
    __shared__ int lcur[BUCKETS];
    __shared__ int gbase[BUCKETS];
    __shared__ unsigned int stage[CHUNK_A];
    int t = threadIdx.x;
    for (int i = t; i <= BUCKETS; i += 1024) lh[i] = 0;
    __syncthreads();

    int e0 = blockIdx.x * CHUNK_A;
    int e1 = min(e0 + CHUNK_A, E_EDGES);

    unsigned int pv[EPT];
    int pb[EPT];
    int cnt = 0;
    for (int i = e0 + t; i < e1; i += 1024) {
        int d = dst[i];
        int b = d >> 8;
        pv[cnt] = (unsigned int)src[i] | (((unsigned int)(d & 255)) << 17);
        pb[cnt] = b;
        ++cnt;
        atomicAdd(&lh[b], 1);
    }
    __syncthreads();

    for (int i = t; i < BUCKETS; i += 1024) lstart[i] = lh[i];
    __syncthreads();
    for (int off = 1; off < 512; off <<= 1) {
        int v = 0;
        if (t < BUCKETS && t >= off) v = lstart[t - off];
        __syncthreads();
        if (t < BUCKETS && t >= off) lstart[t] += v;
        __syncthreads();
    }
    int myIncl = (t < BUCKETS) ? lstart[t] : 0;
    int myCnt  = (t < BUCKETS) ? lh[t] : 0;
    __syncthreads();
    if (t < BUCKETS) {
        int ex = myIncl - myCnt;
        lstart[t] = ex;
        lcur[t] = ex;
        if (myCnt > 0) gbase[t] = t * CAP + atomicAdd(&cursor[t], myCnt);
    }
    if (t == 0) lstart[BUCKETS] = e1 - e0;
    __syncthreads();

    for (int k = 0; k < cnt; ++k) {
        int pos = atomicAdd(&lcur[pb[k]], 1);
        stage[pos] = pv[k];
    }
    __syncthreads();

    int total = e1 - e0;
    for (int i = t; i < total; i += 1024) {
        int lo = 0, hi = BUCKETS;
        while (hi - lo > 1) {
            int mid = (lo + hi) >> 1;
            if (lstart[mid] <= i) lo = mid; else hi = mid;
        }
        pairs[gbase[lo] + (i - lstart[lo])] = stage[i];
    }
}

// ---------------- binB: single pairs read, LDS sort, coalesced csr write ----------
__global__ __launch_bounds__(512) void binB_kernel(const unsigned int* __restrict__ pairs,
                                                   const int* __restrict__ cursor,
                                                   int* __restrict__ deg_i,
                                                   int* __restrict__ offsets,
                                                   int* __restrict__ csr_src) {
    __shared__ int lhist[256];
    __shared__ int lscan[256];
    __shared__ int lcur[256];
    __shared__ unsigned int stage[CAP];
    int b = blockIdx.x;
    int t = threadIdx.x;
    if (t < 256) lhist[t] = 0;
    __syncthreads();
    int start = b * CAP;
    int cntAll = cursor[b];
    unsigned int pv[EPT_B];
    int c = 0;
    for (int i = t; i < cntAll; i += 512) {
        unsigned int p = pairs[start + i];
        pv[c++] = p;
        atomicAdd(&lhist[p >> 17], 1);
    }
    __syncthreads();
    int cnt = (t < 256) ? lhist[t] : 0;
    if (t < 256) lscan[t] = cnt;
    __syncthreads();
    int incl = cnt;
    for (int off = 1; off < 256; off <<= 1) {
        int tmp = (t < 256 && t >= off) ? lscan[t - off] : 0;
        __syncthreads();
        if (t < 256) {
            incl += tmp;
            lscan[t] = incl;
        }
        __syncthreads();
    }
    if (t < 256) {
        int ex = incl - cnt;  // local exclusive offset within bucket
        int node = (b << 8) + t;
        if (node < N_NODES) {
            deg_i[node] = cnt;
            offsets[node] = start + ex;
        }
        lcur[t] = ex;
    }
    __syncthreads();
    for (int k = 0; k < c; ++k) {
        int pos = atomicAdd(&lcur[pv[k] >> 17], 1);
        stage[pos] = pv[k] & 0x1FFFFu;
    }
    __syncthreads();
    for (int i = t; i < cntAll; i += 512)
        csr_src[start + i] = (int)stage[i];
}

// ---------------- fp16 conversion of x ----------------
__global__ void convert_x_kernel(const float* __restrict__ x, __half* __restrict__ xh) {
    int tid = blockIdx.x * blockDim.x + threadIdx.x;
    if (tid >= N_NODES * 12) return;
    int n = tid / 12;
    int f = tid - n * 12;
    xh[tid] = __float2half((f < F_IN) ? x[n * F_IN + f] : 0.0f);
}

// ---------------- layer 1 gather (unchanged) ----------------
__global__ void gather1_kernel(const int* __restrict__ csr_src,
                               const int* __restrict__ offsets,
                               const int* __restrict__ deg_i,
                               const __half2* __restrict__ xh2,
                               float* __restrict__ agg1) {
    int tid = blockIdx.x * blockDim.x + threadIdx.x;
    int n = tid >> 3;
    int f2 = tid & 7;
    if (n >= N_NODES || f2 >= 6) return;
    int start = offsets[n];
    int end = start + deg_i[n];
    float2 a0 = {0.f, 0.f}, a1 = {0.f, 0.f}, a2 = {0.f, 0.f}, a3 = {0.f, 0.f};
    int i = start;
    for (; i + 4 <= end; i += 4) {
        int s0 = csr_src[i], s1 = csr_src[i + 1], s2 = csr_src[i + 2], s3 = csr_src[i + 3];
        float2 v0 = __half22float2(xh2[s0 * 6 + f2]);
        float2 v1 = __half22float2(xh2[s1 * 6 + f2]);
        float2 v2 = __half22float2(xh2[s2 * 6 + f2]);
        float2 v3 = __half22float2(xh2[s3 * 6 + f2]);
        a0.x += v0.x; a0.y += v0.y;
        a1.x += v1.x; a1.y += v1.y;
        a2.x += v2.x; a2.y += v2.y;
        a3.x += v3.x; a3.y += v3.y;
    }
    for (; i < end; ++i) {
        float2 v = __half22float2(xh2[csr_src[i] * 6 + f2]);
        a0.x += v.x; a0.y += v.y;
    }
    float2 r;
    r.x = a0.x + a1.x + a2.x + a3.x;
    r.y = a0.y + a1.y + a2.y + a3.y;
    ((float2*)agg1)[n * 6 + f2] = r;
}

// ---------------- fused layer1 + dual projection via MFMA ----------------
// Block = 64 nodes, 256 threads = 4 waves, 16 nodes/wave.
// Phase A: h(16x64) = relu([agg1*invd | x](16x32) @ [W1l;W1r](32x64) + b1)  [4 MFMA]
// Phase B: [p2|r2](16x64) = h(16x64) @ [W2l|W2r](64x64) (+b2 on R side)     [8 MFMA]
// Fragment layouts (HW-verified, guide §3): A[m=lane&15][k=quad*8+j],
// B[k=quad*8+j][n=lane&15], C/D col=lane&15 row=quad*4+reg.
__global__ __launch_bounds__(256) void layer1_proj_kernel(
        const float* __restrict__ x,
        const float* __restrict__ agg1,
        const int* __restrict__ deg_i,
        const float* __restrict__ W1l,
        const float* __restrict__ W1r,
        const float* __restrict__ b1,
        const float* __restrict__ W2l,
        const float* __restrict__ W2r,
        const float* __restrict__ b2,
        unsigned char* __restrict__ p8,
        float* __restrict__ r2) {
    __shared__ __attribute__((aligned(16))) _Float16 hA1[64][32];
    __shared__ __attribute__((aligned(16))) _Float16 WB1[64][32];  // [n][k] = W1cat[k][n]
    __shared__ __attribute__((aligned(16))) _Float16 WB2[64][64];  // [n][k] = W2cat[k][n]
    __shared__ __attribute__((aligned(16))) _Float16 hS[64][64];
    int t = threadIdx.x;
    int n0 = blockIdx.x * 64;

    // stage WB1: k 0..10 = W1l rows, 11..21 = W1r rows, 22..31 = 0
    for (int i = t; i < 64 * 32; i += 256) {
        int n = i >> 5, k = i & 31;
        float v = 0.0f;
        if (k < F_IN) v = W1l[k * F_H + n];
        else if (k < 2 * F_IN) v = W1r[(k - F_IN) * F_H + n];
        WB1[n][k] = (_Float16)v;
    }
    // stage WB2: n<32 -> W2l[k][n]; n>=32 -> W2r[k][n-32]
    for (int i = t; i < 64 * 64; i += 256) {
        int n = i >> 6, k = i & 63;
        float v = (n < F_E) ? W2l[k * F_E + n] : W2r[k * F_E + (n - F_E)];
        WB2[n][k] = (_Float16)v;
    }
    // stage hA1[node_local][k] = [agg1*invd (11) | x (11) | 0 pad]
    for (int i = t; i < 64 * 32; i += 256) {
        int nl = i >> 5, k = i & 31;
        int n = n0 + nl;
        if (n >= N_NODES) n = N_NODES - 1;  // clamp (stores guarded later)
        float v = 0.0f;
        if (k < F_IN) {
            float invd = 1.0f / fmaxf((float)deg_i[n], 1.0f);
            v = agg1[n * 12 + k] * invd;
        } else if (k < 2 * F_IN) {
            v = x[n * F_IN + (k - F_IN)];
        }
        hA1[nl][k] = (_Float16)v;
    }
    __syncthreads();

    int lane = t & 63;
    int wave = t >> 6;
    int col = lane & 15;
    int quad = lane >> 4;
    int mbase = wave * 16;

    // ---- phase A ----
    f16x8 afrag = *(const f16x8*)&hA1[mbase + col][quad * 8];
    #pragma unroll
    for (int nt = 0; nt < 4; ++nt) {
        f16x8 bfrag = *(const f16x8*)&WB1[nt * 16 + col][quad * 8];
        float bias = b1[nt * 16 + col];
        f32x4 acc = {bias, bias, bias, bias};
        acc = __builtin_amdgcn_mfma_f32_16x16x32_f16(afrag, bfrag, acc, 0, 0, 0);
        #pragma unroll
        for (int r = 0; r < 4; ++r)
            hS[mbase + quad * 4 + r][nt * 16 + col] = (_Float16)fmaxf(acc[r], 0.0f);
    }
    __syncthreads();

    // ---- phase B ----
    f16x8 a0 = *(const f16x8*)&hS[mbase + col][quad * 8];
    f16x8 a1 = *(const f16x8*)&hS[mbase + col][32 + quad * 8];
    #pragma unroll
    for (int nt = 0; nt < 4; ++nt) {
        f16x8 bf0 = *(const f16x8*)&WB2[nt * 16 + col][quad * 8];
        f16x8 bf1 = *(const f16x8*)&WB2[nt * 16 + col][32 + quad * 8];
        f32x4 acc;
        if (nt < 2) {
            acc = (f32x4){0.f, 0.f, 0.f, 0.f};
        } else {
            float bb = b2[(nt - 2) * 16 + col];
            acc = (f32x4){bb, bb, bb, bb};
        }
        acc = __builtin_amdgcn_mfma_f32_16x16x32_f16(a0, bf0, acc, 0, 0, 0);
        acc = __builtin_amdgcn_mfma_f32_16x16x32_f16(a1, bf1, acc, 0, 0, 0);
        #pragma unroll
        for (int r = 0; r < 4; ++r) {
            int node = n0 + mbase + quad * 4 + r;
            if (node < N_NODES) {
                if (nt < 2) {
                    __hip_fp8_e4m3 q((float)acc[r]);
                    p8[(size_t)node * F_E + nt * 16 + col] = (unsigned char)q.__x;
                } else {
                    r2[(size_t)node * F_E + (nt - 2) * 16 + col] = acc[r];
                }
            }
        }
    }
}

// decode 4 packed fp8 e4m3 -> 4 floats
__device__ inline float4 fp8x4_to_f32(unsigned int w) {
    __hip_fp8_e4m3 a, b, c, d;
    a.__x = (__hip_fp8_storage_t)(w & 0xFF);
    b.__x = (__hip_fp8_storage_t)((w >> 8) & 0xFF);
    c.__x = (__hip_fp8_storage_t)((w >> 16) & 0xFF);
    d.__x = (__hip_fp8_storage_t)((w >> 24) & 0xFF);
    return make_float4((float)a, (float)b, (float)c, (float)d);
}

// ---------------- layer 2 fused: fp8 gather (L2-resident 3.2MB) + relu + logits ------
__global__ void layer2_fused_kernel(const int* __restrict__ csr_src,
                                    const int* __restrict__ offsets,
                                    const int* __restrict__ deg_i,
                                    const unsigned int* __restrict__ p8u,  // [N][8] uint
                                    const float* __restrict__ r2,
                                    const float* __restrict__ Wc,
                                    const float* __restrict__ bc,
                                    float* __restrict__ emb,
                                    float* __restrict__ logits) {
    int tid = blockIdx.x * blockDim.x + threadIdx.x;
    int n = tid >> 3;
    int l = tid & 7;
    if (n >= N_NODES) return;
    int start = offsets[n];
    int cnt = deg_i[n];
    int end = start + cnt;
    float ax = 0.f, ay = 0.f, az = 0.f, aw = 0.f;
    float bx = 0.f, by = 0.f, bz = 0.f, bw = 0.f;
    int i = start;
    for (; i + 4 <= end; i += 4) {
        int s0 = csr_src[i], s1 = csr_src[i + 1], s2 = csr_src[i + 2], s3 = csr_src[i + 3];
        unsigned int w0 = p8u[s0 * 8 + l];
        unsigned int w1 = p8u[s1 * 8 + l];
        unsigned int w2 = p8u[s2 * 8 + l];
        unsigned int w3 = p8u[s3 * 8 + l];
        float4 v0 = fp8x4_to_f32(w0);
        float4 v1 = fp8x4_to_f32(w1);
        float4 v2 = fp8x4_to_f32(w2);
        float4 v3 = fp8x4_to_f32(w3);
        ax += v0.x + v2.x; ay += v0.y + v2.y; az += v0.z + v2.z; aw += v0.w + v2.w;
        bx += v1.x + v3.x; by += v1.y + v3.y; bz += v1.z + v3.z; bw += v1.w + v3.w;
    }
    for (; i < end; ++i) {
        float4 v = fp8x4_to_f32(p8u[csr_src[i] * 8 + l]);
        ax += v.x; ay += v.y; az += v.z; aw += v.w;
    }
    float invd = 1.0f / fmaxf((float)cnt, 1.0f);
    const float* rrow = r2 + n * F_E + 4 * l;
    float4 e;
    e.x = fmaxf((ax + bx) * invd + rrow[0], 0.0f);
    e.y = fmaxf((ay + by) * invd + rrow[1], 0.0f);
    e.z = fmaxf((az + bz) * invd + rrow[2], 0.0f);
    e.w = fmaxf((aw + bw) * invd + rrow[3], 0.0f);
    ((float4*)emb)[n * 8 + l] = e;
    const float* wc = Wc + (4 * l) * 3;
    float c0 = e.x * wc[0] + e.y * wc[3] + e.z * wc[6] + e.w * wc[9];
    float c1 = e.x * wc[1] + e.y * wc[4] + e.z * wc[7] + e.w * wc[10];
    float c2 = e.x * wc[2] + e.y * wc[5] + e.z * wc[8] + e.w * wc[11];
    #pragma unroll
    for (int m = 1; m < 8; m <<= 1) {
        c0 += __shfl_xor(c0, m);
        c1 += __shfl_xor(c1, m);
        c2 += __shfl_xor(c2, m);
    }
    if (l == 0) {
        logits[n * 3 + 0] = c0 + bc[0];
        logits[n * 3 + 1] = c1 + bc[1];
        logits[n * 3 + 2] = c2 + bc[2];
    }
}

extern "C" void kernel_launch(void* const* d_in, const int* in_sizes, int n_in,
                              void* d_out, int out_size, void* d_ws, size_t ws_size,
                              hipStream_t stream) {
    const float* x   = (const float*)d_in[0];
    const int*   ei  = (const int*)d_in[1];
    const float* W1l = (const float*)d_in[2];
    const float* W1r = (const float*)d_in[3];
    const float* b1  = (const float*)d_in[4];
    const float* W2l = (const float*)d_in[5];
    const float* W2r = (const float*)d_in[6];
    const float* b2  = (const float*)d_in[7];
    const float* Wc  = (const float*)d_in[8];
    const float* bc  = (const float*)d_in[9];

    const int* src = ei;
    const int* dst = ei + E_EDGES;

    float* out    = (float*)d_out;
    float* logits = out;
    float* emb    = out + (size_t)N_NODES * 3;

    // ws layout (4B units):
    //   deg_i | offsets | cursor(512) | csr_src (BUCKETS*CAP) | pairs (BUCKETS*CAP)
    //   | r2 (32N fp32) | p8 (8N) | xh (6N) | agg1 (12N)
    int* ws_i     = (int*)d_ws;
    int* deg_i    = ws_i;
    int* offsets  = ws_i + N_NODES;
    int* cursor   = ws_i + 2 * N_NODES;
    int* csr_src  = cursor + 512;
    int* region1  = csr_src + (size_t)BUCKETS * CAP;
    unsigned int* pairs = (unsigned int*)region1;
    int* base2    = region1 + (size_t)BUCKETS * CAP;
    float* r2     = (float*)base2;                            // 32N
    unsigned char* p8 = (unsigned char*)(base2 + (size_t)32 * N_NODES);  // 8N units
    __half* xh    = (__half*)(base2 + (size_t)40 * N_NODES);  // 6N units
    float* agg1   = (float*)(base2 + (size_t)46 * N_NODES);   // 12N

    hipMemsetAsync(cursor, 0, 512 * sizeof(int), stream);

    const int BS = 256;

    convert_x_kernel<<<(N_NODES * 12 + BS - 1) / BS, BS, 0, stream>>>(x, xh);
    binA_kernel<<<NWG_A, 1024, 0, stream>>>(src, dst, cursor, pairs);
    binB_kernel<<<BUCKETS, 512, 0, stream>>>(pairs, cursor, deg_i, offsets, csr_src);

    gather1_kernel<<<(N_NODES * 8 + BS - 1) / BS, BS, 0, stream>>>(
        csr_src, offsets, deg_i, (const __half2*)xh, agg1);
    layer1_proj_kernel<<<(N_NODES + 63) / 64, BS, 0, stream>>>(
        x, agg1, deg_i, W1l, W1r, b1, W2l, W2r, b2, p8, r2);
    layer2_fused_kernel<<<(N_NODES * 8 + BS - 1) / BS, BS, 0, stream>>>(
        csr_src, offsets, deg_i, (const unsigned int*)p8, r2, Wc, bc, emb, logits);
}